// Round 10
// baseline (715.955 us; speedup 1.0000x reference)
//
#include <hip/hip_runtime.h>
#include <hip/hip_bf16.h>

#define TT 2048
#define DD 1024
#define NH 16
#define HSZ 64
#define FFD 4096
#define VV 32000
#define NL 2

typedef __bf16 bf16x8 __attribute__((ext_vector_type(8)));
typedef float f32x4 __attribute__((ext_vector_type(4)));

__device__ __forceinline__ unsigned short f2bf(float f) {
    unsigned int u = __float_as_uint(f);
    return (unsigned short)((u + 0x7FFFu + ((u >> 16) & 1u)) >> 16);
}

// async global->LDS, 16B per lane; lds dst is wave-uniform base + lane*16
#define GLL(gsrc, ldst) \
  __builtin_amdgcn_global_load_lds((const __attribute__((address_space(1))) void*)(gsrc), \
                                   (__attribute__((address_space(3))) void*)(ldst), 16, 0, 0)

// XOR swizzles (involutions: XOR bits are disjoint from their key bits)
#define SWZ64(L)  ((L) ^ ((((L) >> 7) & 3) << 4))   // 64B-row tiles (GEMM As/Bs)
#define SWZ128(L) ((L) ^ ((((L) >> 7) & 7) << 4))   // 128B-row tiles (attn Ps + 256q gemm)

#define VMW(n) asm volatile("s_waitcnt vmcnt(" #n ")" ::: "memory")

// ---------------------------------------------------------------------------
__global__ __launch_bounds__(256) void embed_kernel(
    const int* __restrict__ idx, const float* __restrict__ tok,
    const float* __restrict__ pos, float* __restrict__ x)
{
    int t = blockIdx.x;
    int d4 = threadIdx.x * 4;
    int token = idx[t];
    float4 a = *(const float4*)&tok[(size_t)token * DD + d4];
    float4 p = *(const float4*)&pos[(size_t)t * DD + d4];
    float4 r;
    r.x = a.x + p.x; r.y = a.y + p.y; r.z = a.z + p.z; r.w = a.w + p.w;
    *(float4*)&x[(size_t)t * DD + d4] = r;
}

// LayerNorm fp32 -> bf16 out
__global__ __launch_bounds__(256) void ln_kernel(
    const float* __restrict__ x, const float* __restrict__ g,
    const float* __restrict__ b, unsigned short* __restrict__ out)
{
    int t = blockIdx.x;
    int tid = threadIdx.x;
    int d4 = tid * 4;
    float4 xv = *(const float4*)&x[(size_t)t * DD + d4];
    float s  = xv.x + xv.y + xv.z + xv.w;
    float s2 = xv.x*xv.x + xv.y*xv.y + xv.z*xv.z + xv.w*xv.w;
    #pragma unroll
    for (int off = 32; off >= 1; off >>= 1) {
        s  += __shfl_xor(s,  off);
        s2 += __shfl_xor(s2, off);
    }
    __shared__ float ls[4], ls2[4];
    int w = tid >> 6;
    if ((tid & 63) == 0) { ls[w] = s; ls2[w] = s2; }
    __syncthreads();
    float sum  = ls[0] + ls[1] + ls[2] + ls[3];
    float sum2 = ls2[0] + ls2[1] + ls2[2] + ls2[3];
    float mean = sum * (1.0f / DD);
    float var  = sum2 * (1.0f / DD) - mean * mean;
    float r = rsqrtf(var + 1e-5f);
    float4 gv = *(const float4*)&g[d4];
    float4 bv = *(const float4*)&b[d4];
    ushort4 pk;
    pk.x = f2bf((xv.x - mean) * r * gv.x + bv.x);
    pk.y = f2bf((xv.y - mean) * r * gv.y + bv.y);
    pk.z = f2bf((xv.z - mean) * r * gv.z + bv.z);
    pk.w = f2bf((xv.w - mean) * r * gv.w + bv.w);
    *(ushort4*)&out[(size_t)t * DD + d4] = pk;
}

// generic cast+transpose: src [R][C] f32 -> dst [C][R] bf16
__global__ __launch_bounds__(256) void tcast(
    const float* __restrict__ src, unsigned short* __restrict__ dst,
    int R, int C, size_t sstride, size_t dstride)
{
    __shared__ float tile[64][65];
    const float* s = src + (size_t)blockIdx.z * sstride;
    unsigned short* d = dst + (size_t)blockIdx.z * dstride;
    int c0 = blockIdx.x * 64, r0 = blockIdx.y * 64;
    #pragma unroll
    for (int i = 0; i < 16; ++i) {
        int id = i * 256 + threadIdx.x;
        int rr = id >> 6, cc = id & 63;
        tile[rr][cc] = s[(size_t)(r0 + rr) * C + (c0 + cc)];
    }
    __syncthreads();
    #pragma unroll
    for (int i = 0; i < 16; ++i) {
        int id = i * 256 + threadIdx.x;
        int cc = id >> 6, rr = id & 63;
        d[(size_t)(c0 + cc) * R + (r0 + rr)] = f2bf(tile[rr][cc]);
    }
}

// wq/wk/wv [L][H][D][HS] f32 -> wqkvT [L][3072][1024] bf16 (row n = mat*1024+h*64+s, col c)
__global__ __launch_bounds__(256) void qkv_tcast(
    const float* __restrict__ wq, const float* __restrict__ wk,
    const float* __restrict__ wv, unsigned short* __restrict__ dst)
{
    __shared__ float tile[64][65];
    int l = blockIdx.z;
    int mat = blockIdx.y >> 4, hh = blockIdx.y & 15;
    const float* s = (mat == 0) ? wq : (mat == 1) ? wk : wv;
    s += (((size_t)l * NH + hh) * DD) * HSZ;   // [1024][64]
    int r0 = blockIdx.x * 64;
    #pragma unroll
    for (int i = 0; i < 16; ++i) {
        int id = i * 256 + threadIdx.x;
        int rr = id >> 6, cc = id & 63;
        tile[rr][cc] = s[(size_t)(r0 + rr) * HSZ + cc];
    }
    __syncthreads();
    unsigned short* d = dst + (size_t)l * 3072 * DD + ((size_t)mat * DD + hh * HSZ) * DD;
    #pragma unroll
    for (int i = 0; i < 16; ++i) {
        int id = i * 256 + threadIdx.x;
        int cc = id >> 6, rr = id & 63;
        d[(size_t)cc * DD + (r0 + rr)] = f2bf(tile[rr][cc]);
    }
}

// ---------------------------------------------------------------------------
// bf16 MFMA GEMM: C = A[M,Kst](K cols used) * Bt[N,Kst]^T, 128xBN tile,
// BK=32, 4 waves, ring-3 K-tile buffers + counted vmcnt.
// BN=128: 4 GLL/tile/wave (vmcnt 8/4/0). BN=64: 3 GLL/tile/wave (6/3/0).
// EPI 0: QKV split. EPI 1: bf16 relu(acc+bias). EPI 2: fp32 += acc+bias.
// EPI 3: split-K partial (blockIdx.z selects K-half; fp32 plain write).
// ---------------------------------------------------------------------------
template<int EPI, int BN>
__global__ __launch_bounds__(256) void mgemm(
    const unsigned short* __restrict__ A, const unsigned short* __restrict__ Bt,
    const float* __restrict__ bias, void* __restrict__ outp,
    int M, int N, int K, int Kst)
{
    constexpr int FN = BN / 64 * 2;            // n-frags per wave: 4 or 2
    __shared__ unsigned short As[3][128 * 32];
    __shared__ unsigned short Bs[3][BN * 32];
    int tid = threadIdx.x;
    int w = tid >> 6, lane = tid & 63;
    int l15 = lane & 15, l4 = lane >> 4;
    int bm = blockIdx.y * 128, bn = blockIdx.x * BN;
    int wr = (w >> 1) * 64, wc = (w & 1) * (BN / 2);
    if (EPI == 3) {
        int z = blockIdx.z;                    // K-half: offset A/Bt cols, outp plane
        A  += (size_t)z * K;
        Bt += (size_t)z * K;
        outp = (float*)outp + (size_t)z * TT * DD;
    }

    f32x4 zz = {0.f, 0.f, 0.f, 0.f};
    f32x4 acc[4][FN];
    #pragma unroll
    for (int m = 0; m < 4; ++m)
        #pragma unroll
        for (int n = 0; n < FN; ++n) acc[m][n] = zz;

    int t16 = tid * 16;
    int lg = SWZ64(t16);
    int srow = lg >> 6;            // 0..63
    int skel = (lg & 63) >> 1;     // k element offset, multiple of 8
    const unsigned short* aS0 = A + (size_t)(bm + srow) * Kst + skel;
    const unsigned short* aS1 = A + (size_t)(bm + 64 + srow) * Kst + skel;
    const unsigned short* bS0 = Bt + (size_t)(bn + srow) * Kst + skel;
    const unsigned short* bS1 = Bt + (size_t)(bn + 64 + srow) * Kst + skel;

    #define STAGE(t, slot) do { int kk_ = (t) * 32; \
        GLL(aS0 + kk_, (char*)As[slot] + w * 1024); \
        GLL(aS1 + kk_, (char*)As[slot] + 4096 + w * 1024); \
        GLL(bS0 + kk_, (char*)Bs[slot] + w * 1024); \
        if (BN == 128) GLL(bS1 + kk_, (char*)Bs[slot] + 4096 + w * 1024); } while (0)

    int aoff[4], boff[FN];
    #pragma unroll
    for (int m = 0; m < 4; ++m)
        aoff[m] = SWZ64((wr + m * 16 + l15) * 64 + l4 * 16);
    #pragma unroll
    for (int n = 0; n < FN; ++n)
        boff[n] = SWZ64((wc + n * 16 + l15) * 64 + l4 * 16);

    int nt = K >> 5;
    STAGE(0, 0);
    STAGE(1, 1);
    STAGE(2, 2);
    int slot = 0;
    for (int t = 0; t < nt; ++t) {
        if (BN == 128) {
            if (t + 2 < nt)      VMW(8);
            else if (t + 1 < nt) VMW(4);
            else                 VMW(0);
        } else {
            if (t + 2 < nt)      VMW(6);
            else if (t + 1 < nt) VMW(3);
            else                 VMW(0);
        }
        __builtin_amdgcn_sched_barrier(0);
        __builtin_amdgcn_s_barrier();          // all waves: tile t resident
        __builtin_amdgcn_sched_barrier(0);
        bf16x8 af[4], bfr[FN];
        #pragma unroll
        for (int m = 0; m < 4; ++m) af[m] = *(const bf16x8*)((const char*)As[slot] + aoff[m]);
        #pragma unroll
        for (int n = 0; n < FN; ++n) bfr[n] = *(const bf16x8*)((const char*)Bs[slot] + boff[n]);
        #pragma unroll
        for (int m = 0; m < 4; ++m)
            #pragma unroll
            for (int n = 0; n < FN; ++n)
                acc[m][n] = __builtin_amdgcn_mfma_f32_16x16x32_bf16(af[m], bfr[n], acc[m][n], 0, 0, 0);
        __builtin_amdgcn_sched_barrier(0);
        __builtin_amdgcn_s_barrier();          // all waves done reading slot
        __builtin_amdgcn_sched_barrier(0);
        if (t + 3 < nt) STAGE(t + 3, slot);    // refill freed slot
        slot = (slot == 2) ? 0 : slot + 1;
    }
    #undef STAGE

    #pragma unroll
    for (int m = 0; m < 4; ++m) {
        int row0 = bm + wr + m * 16 + l4 * 4;
        #pragma unroll
        for (int n = 0; n < FN; ++n) {
            int col = bn + wc + n * 16 + l15;
            f32x4 v = acc[m][n];
            if (EPI == 0) {
                int mat = col >> 10, hh = (col >> 6) & 15, ss = col & 63;
                unsigned short* base = (unsigned short*)outp + (size_t)mat * ((size_t)NH * TT * HSZ);
                if (mat < 2) {
                    #pragma unroll
                    for (int i = 0; i < 4; ++i)
                        base[((size_t)hh * TT + row0 + i) * HSZ + ss] = f2bf(v[i]);
                } else {
                    ushort4 pk;
                    pk.x = f2bf(v[0]); pk.y = f2bf(v[1]); pk.z = f2bf(v[2]); pk.w = f2bf(v[3]);
                    *(ushort4*)&base[((size_t)hh * HSZ + ss) * TT + row0] = pk;
                }
            } else if (EPI == 1) {
                float bb = bias[col];
                unsigned short* o = (unsigned short*)outp;
                #pragma unroll
                for (int i = 0; i < 4; ++i)
                    o[(size_t)(row0 + i) * FFD + col] = f2bf(fmaxf(v[i] + bb, 0.f));
            } else if (EPI == 2) {
                float bb = bias[col];
                float* xx = (float*)outp;
                #pragma unroll
                for (int i = 0; i < 4; ++i)
                    xx[(size_t)(row0 + i) * DD + col] += v[i] + bb;
            } else {
                float* xx = (float*)outp;
                #pragma unroll
                for (int i = 0; i < 4; ++i)
                    xx[(size_t)(row0 + i) * DD + col] = v[i];
            }
        }
    }
}

// FFN2 split-K reduce: x += P0 + P1 + bias (fixed order -> deterministic)
__global__ __launch_bounds__(256) void ffn2_reduce(
    const float* __restrict__ P, const float* __restrict__ b2,
    float* __restrict__ x)
{
    int t = blockIdx.x;
    int d4 = threadIdx.x * 4;
    size_t o = (size_t)t * DD + d4;
    float4 p0 = *(const float4*)&P[o];
    float4 p1 = *(const float4*)&P[o + (size_t)TT * DD];
    float4 bb = *(const float4*)&b2[d4];
    float4 xv = *(float4*)&x[o];
    xv.x += p0.x + p1.x + bb.x;
    xv.y += p0.y + p1.y + bb.y;
    xv.z += p0.z + p1.z + bb.z;
    xv.w += p0.w + p1.w + bb.w;
    *(float4*)&x[o] = xv;
}

// ---------------------------------------------------------------------------
// 256x256 / BK=64 / 8-wave GEMM for the unembed (C = A * Bt^T, fp32 out+bias).
// R5 version (measured 188 us / 717 TF): 2 K-tile dbuf (128 KiB LDS), counted
// vmcnt(8), 2 barriers per K-tile, setprio around MFMA, XCD-grouped grid.
// ---------------------------------------------------------------------------
__global__ __launch_bounds__(512, 2) void mgemm256(
    const unsigned short* __restrict__ A, const unsigned short* __restrict__ Bt,
    const float* __restrict__ bias, float* __restrict__ outp,
    int M, int N, int K)
{
    __shared__ unsigned short As[2][2][128 * 64];   // [dbuf][half][row*64k]
    __shared__ unsigned short Bs[2][2][128 * 64];
    int tid = threadIdx.x;
    int w = tid >> 6, lane = tid & 63;
    int l15 = lane & 15, l4 = lane >> 4;
    int wr = w >> 2, wc = w & 3;                    // wave grid 2M x 4N
    int bid = blockIdx.x;
    int xcd = bid & 7, j = bid >> 3;                // j 0..127
    int mt = j & 7, p = xcd * 16 + (j >> 3);
    if (p >= N / 256) return;                       // pad blocks exit whole
    int bm = mt * 256, bn = p * 256;

    f32x4 zz = {0.f, 0.f, 0.f, 0.f};
    f32x4 acc[8][4];
    #pragma unroll
    for (int m = 0; m < 8; ++m)
        #pragma unroll
        for (int n = 0; n < 4; ++n) acc[m][n] = zz;

    int L0 = w * 1024 + lane * 16;
    int Ls = SWZ128(L0);
    int srow = Ls >> 7;             // 0..63
    int skel = (Ls & 127) >> 1;     // k elem offset, multiple of 8
    const unsigned short* aS[2], *bS[2];
    aS[0] = A + (size_t)(bm + srow) * K + skel;
    aS[1] = A + (size_t)(bm + 128 + srow) * K + skel;
    bS[0] = Bt + (size_t)(bn + srow) * K + skel;
    bS[1] = Bt + (size_t)(bn + 128 + srow) * K + skel;
    size_t g1 = (size_t)64 * K;     // g=1: +64 rows, same skel (+8192 in LDS)

    #define STAGE6(t, buf) do { int kk_ = (t) * 64; \
        GLL(aS[0] + kk_,      (char*)As[buf][0] + w * 1024); \
        GLL(aS[0] + g1 + kk_, (char*)As[buf][0] + 8192 + w * 1024); \
        GLL(aS[1] + kk_,      (char*)As[buf][1] + w * 1024); \
        GLL(aS[1] + g1 + kk_, (char*)As[buf][1] + 8192 + w * 1024); \
        GLL(bS[0] + kk_,      (char*)Bs[buf][0] + w * 1024); \
        GLL(bS[0] + g1 + kk_, (char*)Bs[buf][0] + 8192 + w * 1024); \
        GLL(bS[1] + kk_,      (char*)Bs[buf][1] + w * 1024); \
        GLL(bS[1] + g1 + kk_, (char*)Bs[buf][1] + 8192 + w * 1024); } while (0)

    int aoff[8][2], boff[4][2];
    #pragma unroll
    for (int m = 0; m < 8; ++m)
        #pragma unroll
        for (int ks = 0; ks < 2; ++ks) {
            int La = (m * 16 + l15) * 128 + ks * 64 + l4 * 16;
            aoff[m][ks] = SWZ128(La);
        }
    #pragma unroll
    for (int n = 0; n < 4; ++n)
        #pragma unroll
        for (int ks = 0; ks < 2; ++ks) {
            int Lb = ((wc & 1) * 64 + n * 16 + l15) * 128 + ks * 64 + l4 * 16;
            boff[n][ks] = SWZ128(Lb);
        }

    int nt = K >> 6;                // 16
    STAGE6(0, 0);
    STAGE6(1, 1);
    for (int t = 0; t < nt; ++t) {
        int buf = t & 1;
        if (t + 1 < nt) VMW(8);
        else            VMW(0);
        __builtin_amdgcn_sched_barrier(0);
        __builtin_amdgcn_s_barrier();            // tile t fully resident
        __builtin_amdgcn_sched_barrier(0);
        const char* ab = (const char*)As[buf][wr];
        const char* bb = (const char*)Bs[buf][wc >> 1];
        bf16x8 bfr[4][2];
        #pragma unroll
        for (int n = 0; n < 4; ++n)
            #pragma unroll
            for (int ks = 0; ks < 2; ++ks)
                bfr[n][ks] = *(const bf16x8*)(bb + boff[n][ks]);
        __builtin_amdgcn_s_setprio(1);
        #pragma unroll
        for (int rh = 0; rh < 2; ++rh) {
            bf16x8 af[4][2];
            #pragma unroll
            for (int mm = 0; mm < 4; ++mm)
                #pragma unroll
                for (int ks = 0; ks < 2; ++ks)
                    af[mm][ks] = *(const bf16x8*)(ab + aoff[rh * 4 + mm][ks]);
            #pragma unroll
            for (int mm = 0; mm < 4; ++mm)
                #pragma unroll
                for (int n = 0; n < 4; ++n) {
                    acc[rh*4+mm][n] = __builtin_amdgcn_mfma_f32_16x16x32_bf16(af[mm][0], bfr[n][0], acc[rh*4+mm][n], 0, 0, 0);
                    acc[rh*4+mm][n] = __builtin_amdgcn_mfma_f32_16x16x32_bf16(af[mm][1], bfr[n][1], acc[rh*4+mm][n], 0, 0, 0);
                }
        }
        __builtin_amdgcn_s_setprio(0);
        __builtin_amdgcn_sched_barrier(0);
        __builtin_amdgcn_s_barrier();            // all waves done with buf
        __builtin_amdgcn_sched_barrier(0);
        if (t + 2 < nt) STAGE6(t + 2, buf);
    }
    #undef STAGE6

    #pragma unroll
    for (int m = 0; m < 8; ++m) {
        int row0 = bm + wr * 128 + m * 16 + l4 * 4;
        #pragma unroll
        for (int n = 0; n < 4; ++n) {
            int col = bn + wc * 64 + n * 16 + l15;
            float bb = bias[col];
            f32x4 v = acc[m][n];
            #pragma unroll
            for (int i = 0; i < 4; ++i)
                outp[(size_t)(row0 + i) * VV + col] = v[i] + bb;
        }
    }
}

// ---------------------------------------------------------------------------
// Flash attention, swapped-QK^T + defer-max. NO K/V LDS staging: per-head K/V
// (512 KB) is L2-resident under the XCD-head-affine mapping (xcd owns heads
// {2x, 2x+1} -> 1 MB per L2), so K/V MFMA fragments load directly from global
// (m169 pattern). Barrier-free: only wave-private P LDS remains.
// Block = (head, 64 q rows), 4 waves x 16 rows, KV tiles of 64.
// qg/kg [H][T][64] bf16, vt [H][64][T] bf16. x += softmax(QK^T * D^-0.5) V.
// ---------------------------------------------------------------------------
__global__ __launch_bounds__(256) void attn_kernel(
    const unsigned short* __restrict__ qg, const unsigned short* __restrict__ kg,
    const unsigned short* __restrict__ vt, float* __restrict__ x)
{
    __shared__ unsigned short Ps[4][16 * 64];   // per wave [q][u] swizzled
    int tid = threadIdx.x;
    int w = tid >> 6, lane = tid & 63;
    int l15 = lane & 15, l4 = lane >> 4;
    // XCD-head-affine, longest-first: xcd = bid&7 owns heads 2x,2x+1
    int bid = blockIdx.x;
    int j = bid >> 3;                           // 0..63 within XCD
    int hh = (bid & 7) * 2 + (j & 1);
    int qb = (31 - (j >> 1)) * 64;

    // Q as B-operand: B[n=q=l15][d = l4*8+j]
    const unsigned short* qrow = qg + ((size_t)hh * TT + qb + w * 16 + l15) * HSZ + l4 * 8;
    bf16x8 qf0 = *(const bf16x8*)(qrow);
    bf16x8 qf1 = *(const bf16x8*)(qrow + 32);

    const char* kbase = (const char*)(kg + (size_t)hh * TT * HSZ);
    const char* vbase = (const char*)(vt + (size_t)hh * HSZ * TT);

    f32x4 zz = {0.f, 0.f, 0.f, 0.f};
    f32x4 o[4];
    #pragma unroll
    for (int i = 0; i < 4; ++i) o[i] = zz;
    float mrun = -INFINITY, lrun = 0.f;   // per lane: row q = l15

    const float scale = 0.03125f;  // D^-0.5
    int nkv = (qb >> 6) + 1;
    for (int ib = 0; ib < nkv; ++ib) {
        int ub = ib * 64;
        bool diag = (ub == qb);

        // S^T = K Q^T : frag f covers u_loc = 16f + l4*4 + i, q = l15.
        // K frags direct from global (L2-hot).
        f32x4 sfr[4];
        __builtin_amdgcn_s_setprio(1);
        #pragma unroll
        for (int f = 0; f < 4; ++f) {
            const char* krow = kbase + (size_t)(ub + f * 16 + l15) * 128 + l4 * 16;
            bf16x8 k0 = *(const bf16x8*)(krow);
            bf16x8 k1 = *(const bf16x8*)(krow + 64);
            f32x4 z = zz;
            z = __builtin_amdgcn_mfma_f32_16x16x32_bf16(k0, qf0, z, 0, 0, 0);
            z = __builtin_amdgcn_mfma_f32_16x16x32_bf16(k1, qf1, z, 0, 0, 0);
            sfr[f] = z;
        }
        __builtin_amdgcn_s_setprio(0);

        // scale + causal mask + row max (all rows parallel; row q = l15)
        float mx = -INFINITY;
        #pragma unroll
        for (int f = 0; f < 4; ++f)
            #pragma unroll
            for (int i = 0; i < 4; ++i) {
                float s = sfr[f][i] * scale;
                if (diag && (16 * f + (l4 << 2) + i) > (w * 16 + l15)) s = -INFINITY;
                sfr[f][i] = s;
                mx = fmaxf(mx, s);
            }
        mx = fmaxf(mx, __shfl_xor(mx, 16));
        mx = fmaxf(mx, __shfl_xor(mx, 32));
        // defer-max (T13): skip m-update + O-rescale unless max grew by > 8
        bool grow = __any(mx > mrun + 8.0f);
        float c = 1.0f;
        if (grow) {
            float mn = fmaxf(mrun, mx);
            c = __expf(mrun - mn);
            mrun = mn;
        }
        float ps = 0.f;
        #pragma unroll
        for (int f = 0; f < 4; ++f)
            #pragma unroll
            for (int i = 0; i < 4; ++i) {
                float p = __expf(sfr[f][i] - mrun);
                sfr[f][i] = p;
                ps += p;
            }
        ps += __shfl_xor(ps, 16);
        ps += __shfl_xor(ps, 32);
        lrun = lrun * c + ps;
        if (grow) {
            // deliver c (at lane l15=q) to output-row lanes (q=l4*4+i)
            #pragma unroll
            for (int i = 0; i < 4; ++i) {
                float ci = __shfl(c, (lane & 48) + (l4 << 2) + i);
                #pragma unroll
                for (int sf = 0; sf < 4; ++sf) o[sf][i] *= ci;
            }
        }

        // write P (bf16, packed pairs) to wave-private swizzled LDS [q][u]
        unsigned short* pw = Ps[w];
        #pragma unroll
        for (int f = 0; f < 4; ++f) {
            unsigned a0 = ((unsigned)f2bf(sfr[f][0])) | (((unsigned)f2bf(sfr[f][1])) << 16);
            unsigned a1 = ((unsigned)f2bf(sfr[f][2])) | (((unsigned)f2bf(sfr[f][3])) << 16);
            int byte0 = l15 * 128 + (16 * f + (l4 << 2)) * 2;
            *(unsigned*)((char*)pw + SWZ128(byte0)) = a0;
            *(unsigned*)((char*)pw + SWZ128(byte0 + 4)) = a1;
        }
        // O += P V   (A = P[q][u] from LDS, B = V^T[d][u] direct from global)
        bf16x8 pa0 = *(const bf16x8*)((const char*)pw + SWZ128(l15 * 128 + l4 * 16));
        bf16x8 pa1 = *(const bf16x8*)((const char*)pw + SWZ128(l15 * 128 + 64 + l4 * 16));
        __builtin_amdgcn_s_setprio(1);
        #pragma unroll
        for (int sf = 0; sf < 4; ++sf) {
            const char* vrow = vbase + (size_t)(sf * 16 + l15) * (TT * 2) + ub * 2 + l4 * 16;
            bf16x8 v0 = *(const bf16x8*)(vrow);
            bf16x8 v1 = *(const bf16x8*)(vrow + 64);
            o[sf] = __builtin_amdgcn_mfma_f32_16x16x32_bf16(pa0, v0, o[sf], 0, 0, 0);
            o[sf] = __builtin_amdgcn_mfma_f32_16x16x32_bf16(pa1, v1, o[sf], 0, 0, 0);
        }
        __builtin_amdgcn_s_setprio(0);
    }
    float rl[4];
    #pragma unroll
    for (int i = 0; i < 4; ++i)
        rl[i] = 1.0f / __shfl(lrun, (lane & 48) + (l4 << 2) + i);
    #pragma unroll
    for (int sf = 0; sf < 4; ++sf)
        #pragma unroll
        for (int i = 0; i < 4; ++i) {
            int q = qb + w * 16 + l4 * 4 + i;
            int d = hh * HSZ + sf * 16 + l15;
            x[(size_t)q * DD + d] += o[sf][i] * rl[i];
        }
}

// ---------------------------------------------------------------------------
extern "C" void kernel_launch(void* const* d_in, const int* in_sizes, int n_in,
                              void* d_out, int out_size, void* d_ws, size_t ws_size,
                              hipStream_t stream)
{
    const int*   idx    = (const int*)  d_in[0];
    const float* tok    = (const float*)d_in[1];
    const float* pos    = (const float*)d_in[2];
    const float* ln1_g  = (const float*)d_in[3];
    const float* ln1_b  = (const float*)d_in[4];
    const float* wq     = (const float*)d_in[5];
    const float* wk     = (const float*)d_in[6];
    const float* wv     = (const float*)d_in[7];
    const float* ln2_g  = (const float*)d_in[8];
    const float* ln2_b  = (const float*)d_in[9];
    const float* w1     = (const float*)d_in[10];
    const float* b1     = (const float*)d_in[11];
    const float* w2     = (const float*)d_in[12];
    const float* b2     = (const float*)d_in[13];
    const float* lnf_g  = (const float*)d_in[14];
    const float* lnf_b  = (const float*)d_in[15];
    const float* w_un   = (const float*)d_in[16];
    const float* b_un   = (const float*)d_in[17];
    float* out = (float*)d_out;

    char* W = (char*)d_ws;
    float*          x    = (float*)(W);                          // 8 MB
    unsigned short* h    = (unsigned short*)(W + 8388608);       // 4 MB
    unsigned short* qg   = (unsigned short*)(W + 12582912);      // 4 MB
    unsigned short* kg   = (unsigned short*)(W + 16777216);      // 4 MB
    unsigned short* vt   = (unsigned short*)(W + 20971520);      // 4 MB
    float*          Pp   = (float*)(W + 8388608);                // 16 MB (h..vt, dead during FFN2)
    unsigned short* h1   = (unsigned short*)(W + 25165824);      // 16 MB
    unsigned short* wqkvT= (unsigned short*)(W + 41943040);      // 12.6 MB
    unsigned short* w1T  = (unsigned short*)(W + 54525952);      // 16.8 MB
    unsigned short* w2T  = (unsigned short*)(W + 71303168);      // 16.8 MB
    unsigned short* wunT = (unsigned short*)(W + 88080384);      // 65.5 MB -> 153.6 MB total
    (void)kg; (void)ws_size; (void)in_sizes; (void)n_in; (void)out_size;

    // weight conversion (per call; ~370 MB traffic)
    qkv_tcast<<<dim3(16, 48, 2), 256, 0, stream>>>(wq, wk, wv, wqkvT);
    tcast<<<dim3(64, 16, 2), 256, 0, stream>>>(w1, w1T, DD, FFD, (size_t)DD * FFD, (size_t)DD * FFD);
    tcast<<<dim3(16, 64, 2), 256, 0, stream>>>(w2, w2T, FFD, DD, (size_t)FFD * DD, (size_t)FFD * DD);
    tcast<<<dim3(500, 16, 1), 256, 0, stream>>>(w_un, wunT, DD, VV, 0, 0);

    embed_kernel<<<TT, 256, 0, stream>>>(idx, tok, pos, x);

    for (int l = 0; l < NL; ++l) {
        ln_kernel<<<TT, 256, 0, stream>>>(x, ln1_g + l * DD, ln1_b + l * DD, h);
        mgemm<0, 64><<<dim3(48, 16), 256, 0, stream>>>(h, wqkvT + (size_t)l * 3072 * DD, nullptr, qg, TT, 3072, DD, DD);
        attn_kernel<<<512, 256, 0, stream>>>(qg, kg, vt, x);
        ln_kernel<<<TT, 256, 0, stream>>>(x, ln2_g + l * DD, ln2_b + l * DD, h);
        mgemm<1, 128><<<dim3(32, 16), 256, 0, stream>>>(h, w1T + (size_t)l * FFD * DD, b1 + (size_t)l * FFD, h1, TT, FFD, DD, DD);
        // FFN2 split-K=2: partials (z-planes) then deterministic reduce
        mgemm<3, 64><<<dim3(16, 16, 2), 256, 0, stream>>>(h1, w2T + (size_t)l * DD * FFD, nullptr, Pp, TT, DD, FFD / 2, FFD);
        ffn2_reduce<<<TT, 256, 0, stream>>>(Pp, b2 + (size_t)l * DD, x);
    }

    ln_kernel<<<TT, 256, 0, stream>>>(x, lnf_g, lnf_b, h);
    mgemm256<<<dim3(1024), 512, 0, stream>>>(h, wunT, b_un, out, TT, VV, DD);
}

// Round 12
// 616.114 us; speedup vs baseline: 1.1620x; 1.1620x over previous
//
#include <hip/hip_runtime.h>
#include <hip/hip_bf16.h>

#define TT 2048
#define DD 1024
#define NH 16
#define HSZ 64
#define FFD 4096
#define VV 32000
#define NL 2

typedef __bf16 bf16x8 __attribute__((ext_vector_type(8)));
typedef float f32x4 __attribute__((ext_vector_type(4)));

__device__ __forceinline__ unsigned short f2bf(float f) {
    unsigned int u = __float_as_uint(f);
    return (unsigned short)((u + 0x7FFFu + ((u >> 16) & 1u)) >> 16);
}

// async global->LDS, 16B per lane; lds dst is wave-uniform base + lane*16
#define GLL(gsrc, ldst) \
  __builtin_amdgcn_global_load_lds((const __attribute__((address_space(1))) void*)(gsrc), \
                                   (__attribute__((address_space(3))) void*)(ldst), 16, 0, 0)

// XOR swizzles (involutions: XOR bits are disjoint from their key bits)
#define SWZ64(L)  ((L) ^ ((((L) >> 7) & 3) << 4))   // 64B-row tiles (GEMM As/Bs)
#define SWZ128(L) ((L) ^ ((((L) >> 7) & 7) << 4))   // 128B-row tiles (attn + 256q gemm)

#define VMW(n) asm volatile("s_waitcnt vmcnt(" #n ")" ::: "memory")

// ---------------------------------------------------------------------------
__global__ __launch_bounds__(256) void embed_kernel(
    const int* __restrict__ idx, const float* __restrict__ tok,
    const float* __restrict__ pos, float* __restrict__ x)
{
    int t = blockIdx.x;
    int d4 = threadIdx.x * 4;
    int token = idx[t];
    float4 a = *(const float4*)&tok[(size_t)token * DD + d4];
    float4 p = *(const float4*)&pos[(size_t)t * DD + d4];
    float4 r;
    r.x = a.x + p.x; r.y = a.y + p.y; r.z = a.z + p.z; r.w = a.w + p.w;
    *(float4*)&x[(size_t)t * DD + d4] = r;
}

// LayerNorm fp32 -> bf16 out
__global__ __launch_bounds__(256) void ln_kernel(
    const float* __restrict__ x, const float* __restrict__ g,
    const float* __restrict__ b, unsigned short* __restrict__ out)
{
    int t = blockIdx.x;
    int tid = threadIdx.x;
    int d4 = tid * 4;
    float4 xv = *(const float4*)&x[(size_t)t * DD + d4];
    float s  = xv.x + xv.y + xv.z + xv.w;
    float s2 = xv.x*xv.x + xv.y*xv.y + xv.z*xv.z + xv.w*xv.w;
    #pragma unroll
    for (int off = 32; off >= 1; off >>= 1) {
        s  += __shfl_xor(s,  off);
        s2 += __shfl_xor(s2, off);
    }
    __shared__ float ls[4], ls2[4];
    int w = tid >> 6;
    if ((tid & 63) == 0) { ls[w] = s; ls2[w] = s2; }
    __syncthreads();
    float sum  = ls[0] + ls[1] + ls[2] + ls[3];
    float sum2 = ls2[0] + ls2[1] + ls2[2] + ls2[3];
    float mean = sum * (1.0f / DD);
    float var  = sum2 * (1.0f / DD) - mean * mean;
    float r = rsqrtf(var + 1e-5f);
    float4 gv = *(const float4*)&g[d4];
    float4 bv = *(const float4*)&b[d4];
    ushort4 pk;
    pk.x = f2bf((xv.x - mean) * r * gv.x + bv.x);
    pk.y = f2bf((xv.y - mean) * r * gv.y + bv.y);
    pk.z = f2bf((xv.z - mean) * r * gv.z + bv.z);
    pk.w = f2bf((xv.w - mean) * r * gv.w + bv.w);
    *(ushort4*)&out[(size_t)t * DD + d4] = pk;
}

// generic cast+transpose: src [R][C] f32 -> dst [C][R] bf16
__global__ __launch_bounds__(256) void tcast(
    const float* __restrict__ src, unsigned short* __restrict__ dst,
    int R, int C, size_t sstride, size_t dstride)
{
    __shared__ float tile[64][65];
    const float* s = src + (size_t)blockIdx.z * sstride;
    unsigned short* d = dst + (size_t)blockIdx.z * dstride;
    int c0 = blockIdx.x * 64, r0 = blockIdx.y * 64;
    #pragma unroll
    for (int i = 0; i < 16; ++i) {
        int id = i * 256 + threadIdx.x;
        int rr = id >> 6, cc = id & 63;
        tile[rr][cc] = s[(size_t)(r0 + rr) * C + (c0 + cc)];
    }
    __syncthreads();
    #pragma unroll
    for (int i = 0; i < 16; ++i) {
        int id = i * 256 + threadIdx.x;
        int cc = id >> 6, rr = id & 63;
        d[(size_t)(c0 + cc) * R + (r0 + rr)] = f2bf(tile[rr][cc]);
    }
}

// wq/wk/wv [L][H][D][HS] f32 -> wqkvT [L][3072][1024] bf16 (row n = mat*1024+h*64+s, col c)
__global__ __launch_bounds__(256) void qkv_tcast(
    const float* __restrict__ wq, const float* __restrict__ wk,
    const float* __restrict__ wv, unsigned short* __restrict__ dst)
{
    __shared__ float tile[64][65];
    int l = blockIdx.z;
    int mat = blockIdx.y >> 4, hh = blockIdx.y & 15;
    const float* s = (mat == 0) ? wq : (mat == 1) ? wk : wv;
    s += (((size_t)l * NH + hh) * DD) * HSZ;   // [1024][64]
    int r0 = blockIdx.x * 64;
    #pragma unroll
    for (int i = 0; i < 16; ++i) {
        int id = i * 256 + threadIdx.x;
        int rr = id >> 6, cc = id & 63;
        tile[rr][cc] = s[(size_t)(r0 + rr) * HSZ + cc];
    }
    __syncthreads();
    unsigned short* d = dst + (size_t)l * 3072 * DD + ((size_t)mat * DD + hh * HSZ) * DD;
    #pragma unroll
    for (int i = 0; i < 16; ++i) {
        int id = i * 256 + threadIdx.x;
        int cc = id >> 6, rr = id & 63;
        d[(size_t)cc * DD + (r0 + rr)] = f2bf(tile[rr][cc]);
    }
}

// ---------------------------------------------------------------------------
// bf16 MFMA GEMM: C = A[M,Kst](K cols used) * Bt[N,Kst]^T, 128xBN tile,
// BK=32, 4 waves, ring-3 K-tile buffers + counted vmcnt.
// BN=128: 4 GLL/tile/wave (vmcnt 8/4/0). BN=64: 3 GLL/tile/wave (6/3/0).
// EPI 0: QKV split. EPI 1: bf16 relu(acc+bias). EPI 2: fp32 += acc+bias.
// EPI 3: split-K partial (blockIdx.z selects K-half; fp32 plain write).
// ---------------------------------------------------------------------------
template<int EPI, int BN>
__global__ __launch_bounds__(256) void mgemm(
    const unsigned short* __restrict__ A, const unsigned short* __restrict__ Bt,
    const float* __restrict__ bias, void* __restrict__ outp,
    int M, int N, int K, int Kst)
{
    constexpr int FN = BN / 64 * 2;            // n-frags per wave: 4 or 2
    __shared__ unsigned short As[3][128 * 32];
    __shared__ unsigned short Bs[3][BN * 32];
    int tid = threadIdx.x;
    int w = tid >> 6, lane = tid & 63;
    int l15 = lane & 15, l4 = lane >> 4;
    int bm = blockIdx.y * 128, bn = blockIdx.x * BN;
    int wr = (w >> 1) * 64, wc = (w & 1) * (BN / 2);
    if (EPI == 3) {
        int z = blockIdx.z;                    // K-half: offset A/Bt cols, outp plane
        A  += (size_t)z * K;
        Bt += (size_t)z * K;
        outp = (float*)outp + (size_t)z * TT * DD;
    }

    f32x4 zz = {0.f, 0.f, 0.f, 0.f};
    f32x4 acc[4][FN];
    #pragma unroll
    for (int m = 0; m < 4; ++m)
        #pragma unroll
        for (int n = 0; n < FN; ++n) acc[m][n] = zz;

    int t16 = tid * 16;
    int lg = SWZ64(t16);
    int srow = lg >> 6;            // 0..63
    int skel = (lg & 63) >> 1;     // k element offset, multiple of 8
    const unsigned short* aS0 = A + (size_t)(bm + srow) * Kst + skel;
    const unsigned short* aS1 = A + (size_t)(bm + 64 + srow) * Kst + skel;
    const unsigned short* bS0 = Bt + (size_t)(bn + srow) * Kst + skel;
    const unsigned short* bS1 = Bt + (size_t)(bn + 64 + srow) * Kst + skel;

    #define STAGE(t, slot) do { int kk_ = (t) * 32; \
        GLL(aS0 + kk_, (char*)As[slot] + w * 1024); \
        GLL(aS1 + kk_, (char*)As[slot] + 4096 + w * 1024); \
        GLL(bS0 + kk_, (char*)Bs[slot] + w * 1024); \
        if (BN == 128) GLL(bS1 + kk_, (char*)Bs[slot] + 4096 + w * 1024); } while (0)

    int aoff[4], boff[FN];
    #pragma unroll
    for (int m = 0; m < 4; ++m)
        aoff[m] = SWZ64((wr + m * 16 + l15) * 64 + l4 * 16);
    #pragma unroll
    for (int n = 0; n < FN; ++n)
        boff[n] = SWZ64((wc + n * 16 + l15) * 64 + l4 * 16);

    int nt = K >> 5;
    STAGE(0, 0);
    STAGE(1, 1);
    STAGE(2, 2);
    int slot = 0;
    for (int t = 0; t < nt; ++t) {
        if (BN == 128) {
            if (t + 2 < nt)      VMW(8);
            else if (t + 1 < nt) VMW(4);
            else                 VMW(0);
        } else {
            if (t + 2 < nt)      VMW(6);
            else if (t + 1 < nt) VMW(3);
            else                 VMW(0);
        }
        __builtin_amdgcn_sched_barrier(0);
        __builtin_amdgcn_s_barrier();          // all waves: tile t resident
        __builtin_amdgcn_sched_barrier(0);
        bf16x8 af[4], bfr[FN];
        #pragma unroll
        for (int m = 0; m < 4; ++m) af[m] = *(const bf16x8*)((const char*)As[slot] + aoff[m]);
        #pragma unroll
        for (int n = 0; n < FN; ++n) bfr[n] = *(const bf16x8*)((const char*)Bs[slot] + boff[n]);
        #pragma unroll
        for (int m = 0; m < 4; ++m)
            #pragma unroll
            for (int n = 0; n < FN; ++n)
                acc[m][n] = __builtin_amdgcn_mfma_f32_16x16x32_bf16(af[m], bfr[n], acc[m][n], 0, 0, 0);
        __builtin_amdgcn_sched_barrier(0);
        __builtin_amdgcn_s_barrier();          // all waves done reading slot
        __builtin_amdgcn_sched_barrier(0);
        if (t + 3 < nt) STAGE(t + 3, slot);    // refill freed slot
        slot = (slot == 2) ? 0 : slot + 1;
    }
    #undef STAGE

    #pragma unroll
    for (int m = 0; m < 4; ++m) {
        int row0 = bm + wr + m * 16 + l4 * 4;
        #pragma unroll
        for (int n = 0; n < FN; ++n) {
            int col = bn + wc + n * 16 + l15;
            f32x4 v = acc[m][n];
            if (EPI == 0) {
                int mat = col >> 10, hh = (col >> 6) & 15, ss = col & 63;
                unsigned short* base = (unsigned short*)outp + (size_t)mat * ((size_t)NH * TT * HSZ);
                if (mat < 2) {
                    #pragma unroll
                    for (int i = 0; i < 4; ++i)
                        base[((size_t)hh * TT + row0 + i) * HSZ + ss] = f2bf(v[i]);
                } else {
                    ushort4 pk;
                    pk.x = f2bf(v[0]); pk.y = f2bf(v[1]); pk.z = f2bf(v[2]); pk.w = f2bf(v[3]);
                    *(ushort4*)&base[((size_t)hh * HSZ + ss) * TT + row0] = pk;
                }
            } else if (EPI == 1) {
                float bb = bias[col];
                unsigned short* o = (unsigned short*)outp;
                #pragma unroll
                for (int i = 0; i < 4; ++i)
                    o[(size_t)(row0 + i) * FFD + col] = f2bf(fmaxf(v[i] + bb, 0.f));
            } else if (EPI == 2) {
                float bb = bias[col];
                float* xx = (float*)outp;
                #pragma unroll
                for (int i = 0; i < 4; ++i)
                    xx[(size_t)(row0 + i) * DD + col] += v[i] + bb;
            } else {
                float* xx = (float*)outp;
                #pragma unroll
                for (int i = 0; i < 4; ++i)
                    xx[(size_t)(row0 + i) * DD + col] = v[i];
            }
        }
    }
}

// FFN2 split-K reduce: x += P0 + P1 + bias (fixed order -> deterministic)
__global__ __launch_bounds__(256) void ffn2_reduce(
    const float* __restrict__ P, const float* __restrict__ b2,
    float* __restrict__ x)
{
    int t = blockIdx.x;
    int d4 = threadIdx.x * 4;
    size_t o = (size_t)t * DD + d4;
    float4 p0 = *(const float4*)&P[o];
    float4 p1 = *(const float4*)&P[o + (size_t)TT * DD];
    float4 bb = *(const float4*)&b2[d4];
    float4 xv = *(float4*)&x[o];
    xv.x += p0.x + p1.x + bb.x;
    xv.y += p0.y + p1.y + bb.y;
    xv.z += p0.z + p1.z + bb.z;
    xv.w += p0.w + p1.w + bb.w;
    *(float4*)&x[o] = xv;
}

// ---------------------------------------------------------------------------
// 256x256 / BK=64 / 8-wave GEMM for the unembed (C = A * Bt^T, fp32 out+bias).
// R5 version (measured 188 us / 717 TF): 2 K-tile dbuf (128 KiB LDS), counted
// vmcnt(8), 2 barriers per K-tile, setprio around MFMA, XCD-grouped grid.
// ---------------------------------------------------------------------------
__global__ __launch_bounds__(512, 2) void mgemm256(
    const unsigned short* __restrict__ A, const unsigned short* __restrict__ Bt,
    const float* __restrict__ bias, float* __restrict__ outp,
    int M, int N, int K)
{
    __shared__ unsigned short As[2][2][128 * 64];   // [dbuf][half][row*64k]
    __shared__ unsigned short Bs[2][2][128 * 64];
    int tid = threadIdx.x;
    int w = tid >> 6, lane = tid & 63;
    int l15 = lane & 15, l4 = lane >> 4;
    int wr = w >> 2, wc = w & 3;                    // wave grid 2M x 4N
    int bid = blockIdx.x;
    int xcd = bid & 7, j = bid >> 3;                // j 0..127
    int mt = j & 7, p = xcd * 16 + (j >> 3);
    if (p >= N / 256) return;                       // pad blocks exit whole
    int bm = mt * 256, bn = p * 256;

    f32x4 zz = {0.f, 0.f, 0.f, 0.f};
    f32x4 acc[8][4];
    #pragma unroll
    for (int m = 0; m < 8; ++m)
        #pragma unroll
        for (int n = 0; n < 4; ++n) acc[m][n] = zz;

    int L0 = w * 1024 + lane * 16;
    int Ls = SWZ128(L0);
    int srow = Ls >> 7;             // 0..63
    int skel = (Ls & 127) >> 1;     // k elem offset, multiple of 8
    const unsigned short* aS[2], *bS[2];
    aS[0] = A + (size_t)(bm + srow) * K + skel;
    aS[1] = A + (size_t)(bm + 128 + srow) * K + skel;
    bS[0] = Bt + (size_t)(bn + srow) * K + skel;
    bS[1] = Bt + (size_t)(bn + 128 + srow) * K + skel;
    size_t g1 = (size_t)64 * K;     // g=1: +64 rows, same skel (+8192 in LDS)

    #define STAGE6(t, buf) do { int kk_ = (t) * 64; \
        GLL(aS[0] + kk_,      (char*)As[buf][0] + w * 1024); \
        GLL(aS[0] + g1 + kk_, (char*)As[buf][0] + 8192 + w * 1024); \
        GLL(aS[1] + kk_,      (char*)As[buf][1] + w * 1024); \
        GLL(aS[1] + g1 + kk_, (char*)As[buf][1] + 8192 + w * 1024); \
        GLL(bS[0] + kk_,      (char*)Bs[buf][0] + w * 1024); \
        GLL(bS[0] + g1 + kk_, (char*)Bs[buf][0] + 8192 + w * 1024); \
        GLL(bS[1] + kk_,      (char*)Bs[buf][1] + w * 1024); \
        GLL(bS[1] + g1 + kk_, (char*)Bs[buf][1] + 8192 + w * 1024); } while (0)

    int aoff[8][2], boff[4][2];
    #pragma unroll
    for (int m = 0; m < 8; ++m)
        #pragma unroll
        for (int ks = 0; ks < 2; ++ks) {
            int La = (m * 16 + l15) * 128 + ks * 64 + l4 * 16;
            aoff[m][ks] = SWZ128(La);
        }
    #pragma unroll
    for (int n = 0; n < 4; ++n)
        #pragma unroll
        for (int ks = 0; ks < 2; ++ks) {
            int Lb = ((wc & 1) * 64 + n * 16 + l15) * 128 + ks * 64 + l4 * 16;
            boff[n][ks] = SWZ128(Lb);
        }

    int nt = K >> 6;                // 16
    STAGE6(0, 0);
    STAGE6(1, 1);
    for (int t = 0; t < nt; ++t) {
        int buf = t & 1;
        if (t + 1 < nt) VMW(8);
        else            VMW(0);
        __builtin_amdgcn_sched_barrier(0);
        __builtin_amdgcn_s_barrier();            // tile t fully resident
        __builtin_amdgcn_sched_barrier(0);
        const char* ab = (const char*)As[buf][wr];
        const char* bb = (const char*)Bs[buf][wc >> 1];
        bf16x8 bfr[4][2];
        #pragma unroll
        for (int n = 0; n < 4; ++n)
            #pragma unroll
            for (int ks = 0; ks < 2; ++ks)
                bfr[n][ks] = *(const bf16x8*)(bb + boff[n][ks]);
        __builtin_amdgcn_s_setprio(1);
        #pragma unroll
        for (int rh = 0; rh < 2; ++rh) {
            bf16x8 af[4][2];
            #pragma unroll
            for (int mm = 0; mm < 4; ++mm)
                #pragma unroll
                for (int ks = 0; ks < 2; ++ks)
                    af[mm][ks] = *(const bf16x8*)(ab + aoff[rh * 4 + mm][ks]);
            #pragma unroll
            for (int mm = 0; mm < 4; ++mm)
                #pragma unroll
                for (int n = 0; n < 4; ++n) {
                    acc[rh*4+mm][n] = __builtin_amdgcn_mfma_f32_16x16x32_bf16(af[mm][0], bfr[n][0], acc[rh*4+mm][n], 0, 0, 0);
                    acc[rh*4+mm][n] = __builtin_amdgcn_mfma_f32_16x16x32_bf16(af[mm][1], bfr[n][1], acc[rh*4+mm][n], 0, 0, 0);
                }
        }
        __builtin_amdgcn_s_setprio(0);
        __builtin_amdgcn_sched_barrier(0);
        __builtin_amdgcn_s_barrier();            // all waves done with buf
        __builtin_amdgcn_sched_barrier(0);
        if (t + 2 < nt) STAGE6(t + 2, buf);
    }
    #undef STAGE6

    #pragma unroll
    for (int m = 0; m < 8; ++m) {
        int row0 = bm + wr * 128 + m * 16 + l4 * 4;
        #pragma unroll
        for (int n = 0; n < 4; ++n) {
            int col = bn + wc * 64 + n * 16 + l15;
            float bb = bias[col];
            f32x4 v = acc[m][n];
            #pragma unroll
            for (int i = 0; i < 4; ++i)
                outp[(size_t)(row0 + i) * VV + col] = v[i] + bb;
        }
    }
}

// ---------------------------------------------------------------------------
// Flash attention (R9 version, measured in the 659us total): swapped-QK^T +
// counted-vmcnt dbuf staging + defer-max + reverse dispatch order.
// Block = (head, 64 q rows), 4 waves x 16 rows, KV tiles of 64.
// qg/kg [H][T][64] bf16, vt [H][64][T] bf16. x += softmax(QK^T * D^-0.5) V.
// ---------------------------------------------------------------------------
__global__ __launch_bounds__(256) void attn_kernel(
    const unsigned short* __restrict__ qg, const unsigned short* __restrict__ kg,
    const unsigned short* __restrict__ vt, float* __restrict__ x)
{
    __shared__ unsigned short Ks[2][64 * 64];   // [u][d] swizzled
    __shared__ unsigned short Vs[2][64 * 64];   // [d][u] swizzled
    __shared__ unsigned short Ps[4][16 * 64];   // per wave [q][u] swizzled
    int tid = threadIdx.x;
    int w = tid >> 6, lane = tid & 63;
    int l15 = lane & 15, l4 = lane >> 4;
    int hh = blockIdx.y;
    int qb = (31 - blockIdx.x) * 64;            // longest first

    // Q as B-operand: B[n=q=l15][d = l4*8+j]
    const unsigned short* qrow = qg + ((size_t)hh * TT + qb + w * 16 + l15) * HSZ + l4 * 8;
    bf16x8 qf0 = *(const bf16x8*)(qrow);
    bf16x8 qf1 = *(const bf16x8*)(qrow + 32);

    int t16 = tid * 16;
    int lgs = SWZ128(t16);
    int surow = lgs >> 7;          // 0..31
    int subyte = lgs & 127;
    const char* kbase = (const char*)(kg + (size_t)hh * TT * HSZ);
    const char* vbase = (const char*)(vt + (size_t)hh * HSZ * TT);

    #define ASTAGE(ib, buf) do { \
        int ub_ = (ib) * 64; \
        GLL(kbase + (size_t)(ub_ + surow) * 128 + subyte,          (char*)Ks[buf] + w * 1024); \
        GLL(kbase + (size_t)(ub_ + 32 + surow) * 128 + subyte,     (char*)Ks[buf] + 4096 + w * 1024); \
        GLL(vbase + (size_t)surow * 4096 + ub_ * 2 + subyte,       (char*)Vs[buf] + w * 1024); \
        GLL(vbase + (size_t)(surow + 32) * 4096 + ub_ * 2 + subyte,(char*)Vs[buf] + 4096 + w * 1024); \
    } while (0)

    f32x4 zz = {0.f, 0.f, 0.f, 0.f};
    f32x4 o[4];
    #pragma unroll
    for (int i = 0; i < 4; ++i) o[i] = zz;
    float mrun = -INFINITY, lrun = 0.f;   // per lane: row q = l15

    const float scale = 0.03125f;  // D^-0.5
    int nkv = (qb >> 6) + 1;
    ASTAGE(0, 0);
    if (nkv > 1) ASTAGE(1, 1);
    int cur = 0;
    for (int ib = 0; ib < nkv; ++ib) {
        bool diag = (ib * 64 == qb);
        // wait this tile's 4 loads only; next tile's 4 stay in flight
        if (ib + 1 < nkv) VMW(4);
        else              VMW(0);
        __builtin_amdgcn_sched_barrier(0);
        __builtin_amdgcn_s_barrier();          // tile ib resident (all waves)
        __builtin_amdgcn_sched_barrier(0);
        const char* ksc = (const char*)Ks[cur];
        const char* vsc = (const char*)Vs[cur];

        // S^T = K Q^T : frag f covers u_loc = 16f + l4*4 + i, q = l15
        f32x4 sfr[4];
        __builtin_amdgcn_s_setprio(1);
        #pragma unroll
        for (int f = 0; f < 4; ++f) {
            int lgb = (f * 16 + l15) * 128 + l4 * 16;
            bf16x8 k0 = *(const bf16x8*)(ksc + SWZ128(lgb));
            bf16x8 k1 = *(const bf16x8*)(ksc + SWZ128(lgb + 64));
            f32x4 z = zz;
            z = __builtin_amdgcn_mfma_f32_16x16x32_bf16(k0, qf0, z, 0, 0, 0);
            z = __builtin_amdgcn_mfma_f32_16x16x32_bf16(k1, qf1, z, 0, 0, 0);
            sfr[f] = z;
        }
        __builtin_amdgcn_s_setprio(0);

        // scale + causal mask + row max (all rows parallel; row q = l15)
        float mx = -INFINITY;
        #pragma unroll
        for (int f = 0; f < 4; ++f)
            #pragma unroll
            for (int i = 0; i < 4; ++i) {
                float s = sfr[f][i] * scale;
                if (diag && (16 * f + (l4 << 2) + i) > (w * 16 + l15)) s = -INFINITY;
                sfr[f][i] = s;
                mx = fmaxf(mx, s);
            }
        mx = fmaxf(mx, __shfl_xor(mx, 16));
        mx = fmaxf(mx, __shfl_xor(mx, 32));
        // defer-max (T13): skip m-update + O-rescale unless max grew by > 8
        bool grow = __any(mx > mrun + 8.0f);
        float c = 1.0f;
        if (grow) {
            float mn = fmaxf(mrun, mx);
            c = __expf(mrun - mn);
            mrun = mn;
        }
        float ps = 0.f;
        #pragma unroll
        for (int f = 0; f < 4; ++f)
            #pragma unroll
            for (int i = 0; i < 4; ++i) {
                float p = __expf(sfr[f][i] - mrun);
                sfr[f][i] = p;
                ps += p;
            }
        ps += __shfl_xor(ps, 16);
        ps += __shfl_xor(ps, 32);
        lrun = lrun * c + ps;
        if (grow) {
            // deliver c (at lane l15=q) to output-row lanes (q=l4*4+i)
            #pragma unroll
            for (int i = 0; i < 4; ++i) {
                float ci = __shfl(c, (lane & 48) + (l4 << 2) + i);
                #pragma unroll
                for (int sf = 0; sf < 4; ++sf) o[sf][i] *= ci;
            }
        }

        // write P (bf16, packed pairs) to wave-private swizzled LDS [q][u]
        unsigned short* pw = Ps[w];
        #pragma unroll
        for (int f = 0; f < 4; ++f) {
            unsigned a0 = ((unsigned)f2bf(sfr[f][0])) | (((unsigned)f2bf(sfr[f][1])) << 16);
            unsigned a1 = ((unsigned)f2bf(sfr[f][2])) | (((unsigned)f2bf(sfr[f][3])) << 16);
            int byte0 = l15 * 128 + (16 * f + (l4 << 2)) * 2;
            *(unsigned*)((char*)pw + SWZ128(byte0)) = a0;
            *(unsigned*)((char*)pw + SWZ128(byte0 + 4)) = a1;
        }
        // O += P V   (A = P[q][u], B = V^T[d][u])
        bf16x8 pa0 = *(const bf16x8*)((const char*)pw + SWZ128(l15 * 128 + l4 * 16));
        bf16x8 pa1 = *(const bf16x8*)((const char*)pw + SWZ128(l15 * 128 + 64 + l4 * 16));
        __builtin_amdgcn_s_setprio(1);
        #pragma unroll
        for (int sf = 0; sf < 4; ++sf) {
            int lgb = (sf * 16 + l15) * 128 + l4 * 16;
            bf16x8 v0 = *(const bf16x8*)(vsc + SWZ128(lgb));
            bf16x8 v1 = *(const bf16x8*)(vsc + SWZ128(lgb + 64));
            o[sf] = __builtin_amdgcn_mfma_f32_16x16x32_bf16(pa0, v0, o[sf], 0, 0, 0);
            o[sf] = __builtin_amdgcn_mfma_f32_16x16x32_bf16(pa1, v1, o[sf], 0, 0, 0);
        }
        __builtin_amdgcn_s_setprio(0);
        __builtin_amdgcn_sched_barrier(0);
        __builtin_amdgcn_s_barrier();          // all waves done reading cur
        __builtin_amdgcn_sched_barrier(0);
        if (ib + 2 < nkv) ASTAGE(ib + 2, cur); // refill freed buffer
        cur ^= 1;
    }
    #undef ASTAGE
    float rl[4];
    #pragma unroll
    for (int i = 0; i < 4; ++i)
        rl[i] = 1.0f / __shfl(lrun, (lane & 48) + (l4 << 2) + i);
    #pragma unroll
    for (int sf = 0; sf < 4; ++sf)
        #pragma unroll
        for (int i = 0; i < 4; ++i) {
            int q = qb + w * 16 + l4 * 4 + i;
            int d = hh * HSZ + sf * 16 + l15;
            x[(size_t)q * DD + d] += o[sf][i] * rl[i];
        }
}

// ---------------------------------------------------------------------------
extern "C" void kernel_launch(void* const* d_in, const int* in_sizes, int n_in,
                              void* d_out, int out_size, void* d_ws, size_t ws_size,
                              hipStream_t stream)
{
    const int*   idx    = (const int*)  d_in[0];
    const float* tok    = (const float*)d_in[1];
    const float* pos    = (const float*)d_in[2];
    const float* ln1_g  = (const float*)d_in[3];
    const float* ln1_b  = (const float*)d_in[4];
    const float* wq     = (const float*)d_in[5];
    const float* wk     = (const float*)d_in[6];
    const float* wv     = (const float*)d_in[7];
    const float* ln2_g  = (const float*)d_in[8];
    const float* ln2_b  = (const float*)d_in[9];
    const float* w1     = (const float*)d_in[10];
    const float* b1     = (const float*)d_in[11];
    const float* w2     = (const float*)d_in[12];
    const float* b2     = (const float*)d_in[13];
    const float* lnf_g  = (const float*)d_in[14];
    const float* lnf_b  = (const float*)d_in[15];
    const float* w_un   = (const float*)d_in[16];
    const float* b_un   = (const float*)d_in[17];
    float* out = (float*)d_out;

    char* W = (char*)d_ws;
    float*          x    = (float*)(W);                          // 8 MB
    unsigned short* h    = (unsigned short*)(W + 8388608);       // 4 MB
    unsigned short* qg   = (unsigned short*)(W + 12582912);      // 4 MB
    unsigned short* kg   = (unsigned short*)(W + 16777216);      // 4 MB
    unsigned short* vt   = (unsigned short*)(W + 20971520);      // 4 MB
    float*          Pp   = (float*)(W + 8388608);                // 16 MB, aliases h/qg/kg/vt
                                                                 // (all dead during FFN2; R10-verified)
    unsigned short* h1   = (unsigned short*)(W + 25165824);      // 16 MB
    unsigned short* wqkvT= (unsigned short*)(W + 41943040);      // 12.6 MB
    unsigned short* w1T  = (unsigned short*)(W + 54525952);      // 16.8 MB
    unsigned short* w2T  = (unsigned short*)(W + 71303168);      // 16.8 MB
    unsigned short* wunT = (unsigned short*)(W + 88080384);      // 65.5 MB -> 153.6 MB total
    (void)kg; (void)ws_size; (void)in_sizes; (void)n_in; (void)out_size;

    // weight conversion (per call; ~370 MB traffic)
    qkv_tcast<<<dim3(16, 48, 2), 256, 0, stream>>>(wq, wk, wv, wqkvT);
    tcast<<<dim3(64, 16, 2), 256, 0, stream>>>(w1, w1T, DD, FFD, (size_t)DD * FFD, (size_t)DD * FFD);
    tcast<<<dim3(16, 64, 2), 256, 0, stream>>>(w2, w2T, FFD, DD, (size_t)FFD * DD, (size_t)FFD * DD);
    tcast<<<dim3(500, 16, 1), 256, 0, stream>>>(w_un, wunT, DD, VV, 0, 0);

    embed_kernel<<<TT, 256, 0, stream>>>(idx, tok, pos, x);

    for (int l = 0; l < NL; ++l) {
        ln_kernel<<<TT, 256, 0, stream>>>(x, ln1_g + l * DD, ln1_b + l * DD, h);
        mgemm<0, 64><<<dim3(48, 16), 256, 0, stream>>>(h, wqkvT + (size_t)l * 3072 * DD, nullptr, qg, TT, 3072, DD, DD);
        attn_kernel<<<dim3(32, 16), 256, 0, stream>>>(qg, kg, vt, x);
        ln_kernel<<<TT, 256, 0, stream>>>(x, ln2_g + l * DD, ln2_b + l * DD, h);
        mgemm<1, 128><<<dim3(32, 16), 256, 0, stream>>>(h, w1T + (size_t)l * FFD * DD, b1 + (size_t)l * FFD, h1, TT, FFD, DD, DD);
        // FFN2 split-K=2: partials (z-planes) then deterministic reduce
        mgemm<3, 64><<<dim3(16, 16, 2), 256, 0, stream>>>(h1, w2T + (size_t)l * DD * FFD, nullptr, Pp, TT, DD, FFD / 2, FFD);
        ffn2_reduce<<<TT, 256, 0, stream>>>(Pp, b2 + (size_t)l * DD, x);
    }

    ln_kernel<<<TT, 256, 0, stream>>>(x, lnf_g, lnf_b, h);
    mgemm256<<<dim3(1024), 512, 0, stream>>>(h, wunT, b_un, out, TT, VV, DD);
}

// Round 13
// 599.866 us; speedup vs baseline: 1.1935x; 1.0271x over previous
//
#include <hip/hip_runtime.h>
#include <hip/hip_bf16.h>

#define TT 2048
#define DD 1024
#define NH 16
#define HSZ 64
#define FFD 4096
#define VV 32000
#define NL 2

typedef __bf16 bf16x8 __attribute__((ext_vector_type(8)));
typedef float f32x4 __attribute__((ext_vector_type(4)));

__device__ __forceinline__ unsigned short f2bf(float f) {
    unsigned int u = __float_as_uint(f);
    return (unsigned short)((u + 0x7FFFu + ((u >> 16) & 1u)) >> 16);
}

// async global->LDS, 16B per lane; lds dst is wave-uniform base + lane*16
#define GLL(gsrc, ldst) \
  __builtin_amdgcn_global_load_lds((const __attribute__((address_space(1))) void*)(gsrc), \
                                   (__attribute__((address_space(3))) void*)(ldst), 16, 0, 0)

// XOR swizzles (involutions: XOR bits are disjoint from their key bits)
#define SWZ64(L)  ((L) ^ ((((L) >> 7) & 3) << 4))   // 64B-row tiles (GEMM As/Bs)
#define SWZ128(L) ((L) ^ ((((L) >> 7) & 7) << 4))   // 128B-row tiles (attn + 256q gemm)

#define VMW(n) asm volatile("s_waitcnt vmcnt(" #n ")" ::: "memory")

// ---------------------------------------------------------------------------
// Embedding fused with LN1(layer0): block = row t; writes x (fp32) and h (bf16)
// ---------------------------------------------------------------------------
__global__ __launch_bounds__(256) void embed_ln(
    const int* __restrict__ idx, const float* __restrict__ tok,
    const float* __restrict__ pos, const float* __restrict__ g,
    const float* __restrict__ b, float* __restrict__ x,
    unsigned short* __restrict__ h)
{
    int t = blockIdx.x;
    int tid = threadIdx.x;
    int d4 = tid * 4;
    int token = idx[t];
    float4 a = *(const float4*)&tok[(size_t)token * DD + d4];
    float4 p = *(const float4*)&pos[(size_t)t * DD + d4];
    float4 xv;
    xv.x = a.x + p.x; xv.y = a.y + p.y; xv.z = a.z + p.z; xv.w = a.w + p.w;
    *(float4*)&x[(size_t)t * DD + d4] = xv;
    float s  = xv.x + xv.y + xv.z + xv.w;
    float s2 = xv.x*xv.x + xv.y*xv.y + xv.z*xv.z + xv.w*xv.w;
    #pragma unroll
    for (int off = 32; off >= 1; off >>= 1) {
        s  += __shfl_xor(s,  off);
        s2 += __shfl_xor(s2, off);
    }
    __shared__ float ls[4], ls2[4];
    int w = tid >> 6;
    if ((tid & 63) == 0) { ls[w] = s; ls2[w] = s2; }
    __syncthreads();
    float sum  = ls[0] + ls[1] + ls[2] + ls[3];
    float sum2 = ls2[0] + ls2[1] + ls2[2] + ls2[3];
    float mean = sum * (1.0f / DD);
    float var  = sum2 * (1.0f / DD) - mean * mean;
    float r = rsqrtf(var + 1e-5f);
    float4 gv = *(const float4*)&g[d4];
    float4 bv = *(const float4*)&b[d4];
    ushort4 pk;
    pk.x = f2bf((xv.x - mean) * r * gv.x + bv.x);
    pk.y = f2bf((xv.y - mean) * r * gv.y + bv.y);
    pk.z = f2bf((xv.z - mean) * r * gv.z + bv.z);
    pk.w = f2bf((xv.w - mean) * r * gv.w + bv.w);
    *(ushort4*)&h[(size_t)t * DD + d4] = pk;
}

// LayerNorm fp32 -> bf16 out (used for ln2)
__global__ __launch_bounds__(256) void ln_kernel(
    const float* __restrict__ x, const float* __restrict__ g,
    const float* __restrict__ b, unsigned short* __restrict__ out)
{
    int t = blockIdx.x;
    int tid = threadIdx.x;
    int d4 = tid * 4;
    float4 xv = *(const float4*)&x[(size_t)t * DD + d4];
    float s  = xv.x + xv.y + xv.z + xv.w;
    float s2 = xv.x*xv.x + xv.y*xv.y + xv.z*xv.z + xv.w*xv.w;
    #pragma unroll
    for (int off = 32; off >= 1; off >>= 1) {
        s  += __shfl_xor(s,  off);
        s2 += __shfl_xor(s2, off);
    }
    __shared__ float ls[4], ls2[4];
    int w = tid >> 6;
    if ((tid & 63) == 0) { ls[w] = s; ls2[w] = s2; }
    __syncthreads();
    float sum  = ls[0] + ls[1] + ls[2] + ls[3];
    float sum2 = ls2[0] + ls2[1] + ls2[2] + ls2[3];
    float mean = sum * (1.0f / DD);
    float var  = sum2 * (1.0f / DD) - mean * mean;
    float r = rsqrtf(var + 1e-5f);
    float4 gv = *(const float4*)&g[d4];
    float4 bv = *(const float4*)&b[d4];
    ushort4 pk;
    pk.x = f2bf((xv.x - mean) * r * gv.x + bv.x);
    pk.y = f2bf((xv.y - mean) * r * gv.y + bv.y);
    pk.z = f2bf((xv.z - mean) * r * gv.z + bv.z);
    pk.w = f2bf((xv.w - mean) * r * gv.w + bv.w);
    *(ushort4*)&out[(size_t)t * DD + d4] = pk;
}

// generic cast+transpose: src [R][C] f32 -> dst [C][R] bf16
__global__ __launch_bounds__(256) void tcast(
    const float* __restrict__ src, unsigned short* __restrict__ dst,
    int R, int C, size_t sstride, size_t dstride)
{
    __shared__ float tile[64][65];
    const float* s = src + (size_t)blockIdx.z * sstride;
    unsigned short* d = dst + (size_t)blockIdx.z * dstride;
    int c0 = blockIdx.x * 64, r0 = blockIdx.y * 64;
    #pragma unroll
    for (int i = 0; i < 16; ++i) {
        int id = i * 256 + threadIdx.x;
        int rr = id >> 6, cc = id & 63;
        tile[rr][cc] = s[(size_t)(r0 + rr) * C + (c0 + cc)];
    }
    __syncthreads();
    #pragma unroll
    for (int i = 0; i < 16; ++i) {
        int id = i * 256 + threadIdx.x;
        int cc = id >> 6, rr = id & 63;
        d[(size_t)(c0 + cc) * R + (r0 + rr)] = f2bf(tile[rr][cc]);
    }
}

// wq/wk/wv [L][H][D][HS] f32 -> wqkvT [L][3072][1024] bf16 (row n = mat*1024+h*64+s, col c)
__global__ __launch_bounds__(256) void qkv_tcast(
    const float* __restrict__ wq, const float* __restrict__ wk,
    const float* __restrict__ wv, unsigned short* __restrict__ dst)
{
    __shared__ float tile[64][65];
    int l = blockIdx.z;
    int mat = blockIdx.y >> 4, hh = blockIdx.y & 15;
    const float* s = (mat == 0) ? wq : (mat == 1) ? wk : wv;
    s += (((size_t)l * NH + hh) * DD) * HSZ;   // [1024][64]
    int r0 = blockIdx.x * 64;
    #pragma unroll
    for (int i = 0; i < 16; ++i) {
        int id = i * 256 + threadIdx.x;
        int rr = id >> 6, cc = id & 63;
        tile[rr][cc] = s[(size_t)(r0 + rr) * HSZ + cc];
    }
    __syncthreads();
    unsigned short* d = dst + (size_t)l * 3072 * DD + ((size_t)mat * DD + hh * HSZ) * DD;
    #pragma unroll
    for (int i = 0; i < 16; ++i) {
        int id = i * 256 + threadIdx.x;
        int cc = id >> 6, rr = id & 63;
        d[(size_t)cc * DD + (r0 + rr)] = f2bf(tile[rr][cc]);
    }
}

// ---------------------------------------------------------------------------
// bf16 MFMA GEMM: C = A[M,Kst](K cols used) * Bt[N,Kst]^T, 128xBN tile,
// BK=32, 4 waves, ring-3 K-tile buffers + counted vmcnt.
// BN=128: 4 GLL/tile/wave (vmcnt 8/4/0). BN=64: 3 GLL/tile/wave (6/3/0).
// EPI 0: QKV split. EPI 1: bf16 relu(acc+bias). EPI 2: fp32 += acc+bias.
// EPI 3: split-K partial (blockIdx.z selects K-half; fp32 plain write).
// ---------------------------------------------------------------------------
template<int EPI, int BN>
__global__ __launch_bounds__(256) void mgemm(
    const unsigned short* __restrict__ A, const unsigned short* __restrict__ Bt,
    const float* __restrict__ bias, void* __restrict__ outp,
    int M, int N, int K, int Kst)
{
    constexpr int FN = BN / 64 * 2;            // n-frags per wave: 4 or 2
    __shared__ unsigned short As[3][128 * 32];
    __shared__ unsigned short Bs[3][BN * 32];
    int tid = threadIdx.x;
    int w = tid >> 6, lane = tid & 63;
    int l15 = lane & 15, l4 = lane >> 4;
    int bm = blockIdx.y * 128, bn = blockIdx.x * BN;
    int wr = (w >> 1) * 64, wc = (w & 1) * (BN / 2);
    if (EPI == 3) {
        int z = blockIdx.z;                    // K-half: offset A/Bt cols, outp plane
        A  += (size_t)z * K;
        Bt += (size_t)z * K;
        outp = (float*)outp + (size_t)z * TT * DD;
    }

    f32x4 zz = {0.f, 0.f, 0.f, 0.f};
    f32x4 acc[4][FN];
    #pragma unroll
    for (int m = 0; m < 4; ++m)
        #pragma unroll
        for (int n = 0; n < FN; ++n) acc[m][n] = zz;

    int t16 = tid * 16;
    int lg = SWZ64(t16);
    int srow = lg >> 6;            // 0..63
    int skel = (lg & 63) >> 1;     // k element offset, multiple of 8
    const unsigned short* aS0 = A + (size_t)(bm + srow) * Kst + skel;
    const unsigned short* aS1 = A + (size_t)(bm + 64 + srow) * Kst + skel;
    const unsigned short* bS0 = Bt + (size_t)(bn + srow) * Kst + skel;
    const unsigned short* bS1 = Bt + (size_t)(bn + 64 + srow) * Kst + skel;

    #define STAGE(t, slot) do { int kk_ = (t) * 32; \
        GLL(aS0 + kk_, (char*)As[slot] + w * 1024); \
        GLL(aS1 + kk_, (char*)As[slot] + 4096 + w * 1024); \
        GLL(bS0 + kk_, (char*)Bs[slot] + w * 1024); \
        if (BN == 128) GLL(bS1 + kk_, (char*)Bs[slot] + 4096 + w * 1024); } while (0)

    int aoff[4], boff[FN];
    #pragma unroll
    for (int m = 0; m < 4; ++m)
        aoff[m] = SWZ64((wr + m * 16 + l15) * 64 + l4 * 16);
    #pragma unroll
    for (int n = 0; n < FN; ++n)
        boff[n] = SWZ64((wc + n * 16 + l15) * 64 + l4 * 16);

    int nt = K >> 5;
    STAGE(0, 0);
    STAGE(1, 1);
    STAGE(2, 2);
    int slot = 0;
    for (int t = 0; t < nt; ++t) {
        if (BN == 128) {
            if (t + 2 < nt)      VMW(8);
            else if (t + 1 < nt) VMW(4);
            else                 VMW(0);
        } else {
            if (t + 2 < nt)      VMW(6);
            else if (t + 1 < nt) VMW(3);
            else                 VMW(0);
        }
        __builtin_amdgcn_sched_barrier(0);
        __builtin_amdgcn_s_barrier();          // all waves: tile t resident
        __builtin_amdgcn_sched_barrier(0);
        bf16x8 af[4], bfr[FN];
        #pragma unroll
        for (int m = 0; m < 4; ++m) af[m] = *(const bf16x8*)((const char*)As[slot] + aoff[m]);
        #pragma unroll
        for (int n = 0; n < FN; ++n) bfr[n] = *(const bf16x8*)((const char*)Bs[slot] + boff[n]);
        #pragma unroll
        for (int m = 0; m < 4; ++m)
            #pragma unroll
            for (int n = 0; n < FN; ++n)
                acc[m][n] = __builtin_amdgcn_mfma_f32_16x16x32_bf16(af[m], bfr[n], acc[m][n], 0, 0, 0);
        __builtin_amdgcn_sched_barrier(0);
        __builtin_amdgcn_s_barrier();          // all waves done reading slot
        __builtin_amdgcn_sched_barrier(0);
        if (t + 3 < nt) STAGE(t + 3, slot);    // refill freed slot
        slot = (slot == 2) ? 0 : slot + 1;
    }
    #undef STAGE

    #pragma unroll
    for (int m = 0; m < 4; ++m) {
        int row0 = bm + wr + m * 16 + l4 * 4;
        #pragma unroll
        for (int n = 0; n < FN; ++n) {
            int col = bn + wc + n * 16 + l15;
            f32x4 v = acc[m][n];
            if (EPI == 0) {
                int mat = col >> 10, hh = (col >> 6) & 15, ss = col & 63;
                unsigned short* base = (unsigned short*)outp + (size_t)mat * ((size_t)NH * TT * HSZ);
                if (mat < 2) {
                    #pragma unroll
                    for (int i = 0; i < 4; ++i)
                        base[((size_t)hh * TT + row0 + i) * HSZ + ss] = f2bf(v[i]);
                } else {
                    ushort4 pk;
                    pk.x = f2bf(v[0]); pk.y = f2bf(v[1]); pk.z = f2bf(v[2]); pk.w = f2bf(v[3]);
                    *(ushort4*)&base[((size_t)hh * HSZ + ss) * TT + row0] = pk;
                }
            } else if (EPI == 1) {
                float bb = bias[col];
                unsigned short* o = (unsigned short*)outp;
                #pragma unroll
                for (int i = 0; i < 4; ++i)
                    o[(size_t)(row0 + i) * FFD + col] = f2bf(fmaxf(v[i] + bb, 0.f));
            } else if (EPI == 2) {
                float bb = bias[col];
                float* xx = (float*)outp;
                #pragma unroll
                for (int i = 0; i < 4; ++i)
                    xx[(size_t)(row0 + i) * DD + col] += v[i] + bb;
            } else {
                float* xx = (float*)outp;
                #pragma unroll
                for (int i = 0; i < 4; ++i)
                    xx[(size_t)(row0 + i) * DD + col] = v[i];
            }
        }
    }
}

// FFN2 split-K reduce fused with following LN:
// block = row t. x += P0 + P1 + b2 (write x), then h = LN(x; g, b) bf16.
__global__ __launch_bounds__(256) void ffn2_reduce_ln(
    const float* __restrict__ P, const float* __restrict__ b2,
    float* __restrict__ x, const float* __restrict__ g,
    const float* __restrict__ b, unsigned short* __restrict__ h)
{
    int t = blockIdx.x;
    int tid = threadIdx.x;
    int d4 = tid * 4;
    size_t o = (size_t)t * DD + d4;
    float4 p0 = *(const float4*)&P[o];
    float4 p1 = *(const float4*)&P[o + (size_t)TT * DD];
    float4 bb = *(const float4*)&b2[d4];
    float4 xv = *(float4*)&x[o];
    xv.x += p0.x + p1.x + bb.x;
    xv.y += p0.y + p1.y + bb.y;
    xv.z += p0.z + p1.z + bb.z;
    xv.w += p0.w + p1.w + bb.w;
    *(float4*)&x[o] = xv;
    float s  = xv.x + xv.y + xv.z + xv.w;
    float s2 = xv.x*xv.x + xv.y*xv.y + xv.z*xv.z + xv.w*xv.w;
    #pragma unroll
    for (int off = 32; off >= 1; off >>= 1) {
        s  += __shfl_xor(s,  off);
        s2 += __shfl_xor(s2, off);
    }
    __shared__ float ls[4], ls2[4];
    int w = tid >> 6;
    if ((tid & 63) == 0) { ls[w] = s; ls2[w] = s2; }
    __syncthreads();
    float sum  = ls[0] + ls[1] + ls[2] + ls[3];
    float sum2 = ls2[0] + ls2[1] + ls2[2] + ls2[3];
    float mean = sum * (1.0f / DD);
    float var  = sum2 * (1.0f / DD) - mean * mean;
    float r = rsqrtf(var + 1e-5f);
    float4 gv = *(const float4*)&g[d4];
    float4 bv = *(const float4*)&b[d4];
    ushort4 pk;
    pk.x = f2bf((xv.x - mean) * r * gv.x + bv.x);
    pk.y = f2bf((xv.y - mean) * r * gv.y + bv.y);
    pk.z = f2bf((xv.z - mean) * r * gv.z + bv.z);
    pk.w = f2bf((xv.w - mean) * r * gv.w + bv.w);
    *(ushort4*)&h[o] = pk;
}

// ---------------------------------------------------------------------------
// 256x256 / BK=64 / 8-wave GEMM for the unembed (C = A * Bt^T, fp32 out+bias).
// R5 version (measured 188 us / 717 TF): 2 K-tile dbuf (128 KiB LDS), counted
// vmcnt(8), 2 barriers per K-tile, setprio around MFMA, XCD-grouped grid.
// ---------------------------------------------------------------------------
__global__ __launch_bounds__(512, 2) void mgemm256(
    const unsigned short* __restrict__ A, const unsigned short* __restrict__ Bt,
    const float* __restrict__ bias, float* __restrict__ outp,
    int M, int N, int K)
{
    __shared__ unsigned short As[2][2][128 * 64];   // [dbuf][half][row*64k]
    __shared__ unsigned short Bs[2][2][128 * 64];
    int tid = threadIdx.x;
    int w = tid >> 6, lane = tid & 63;
    int l15 = lane & 15, l4 = lane >> 4;
    int wr = w >> 2, wc = w & 3;                    // wave grid 2M x 4N
    int bid = blockIdx.x;
    int xcd = bid & 7, j = bid >> 3;                // j 0..127
    int mt = j & 7, p = xcd * 16 + (j >> 3);
    if (p >= N / 256) return;                       // pad blocks exit whole
    int bm = mt * 256, bn = p * 256;

    f32x4 zz = {0.f, 0.f, 0.f, 0.f};
    f32x4 acc[8][4];
    #pragma unroll
    for (int m = 0; m < 8; ++m)
        #pragma unroll
        for (int n = 0; n < 4; ++n) acc[m][n] = zz;

    int L0 = w * 1024 + lane * 16;
    int Ls = SWZ128(L0);
    int srow = Ls >> 7;             // 0..63
    int skel = (Ls & 127) >> 1;     // k elem offset, multiple of 8
    const unsigned short* aS[2], *bS[2];
    aS[0] = A + (size_t)(bm + srow) * K + skel;
    aS[1] = A + (size_t)(bm + 128 + srow) * K + skel;
    bS[0] = Bt + (size_t)(bn + srow) * K + skel;
    bS[1] = Bt + (size_t)(bn + 128 + srow) * K + skel;
    size_t g1 = (size_t)64 * K;     // g=1: +64 rows, same skel (+8192 in LDS)

    #define STAGE6(t, buf) do { int kk_ = (t) * 64; \
        GLL(aS[0] + kk_,      (char*)As[buf][0] + w * 1024); \
        GLL(aS[0] + g1 + kk_, (char*)As[buf][0] + 8192 + w * 1024); \
        GLL(aS[1] + kk_,      (char*)As[buf][1] + w * 1024); \
        GLL(aS[1] + g1 + kk_, (char*)As[buf][1] + 8192 + w * 1024); \
        GLL(bS[0] + kk_,      (char*)Bs[buf][0] + w * 1024); \
        GLL(bS[0] + g1 + kk_, (char*)Bs[buf][0] + 8192 + w * 1024); \
        GLL(bS[1] + kk_,      (char*)Bs[buf][1] + w * 1024); \
        GLL(bS[1] + g1 + kk_, (char*)Bs[buf][1] + 8192 + w * 1024); } while (0)

    int aoff[8][2], boff[4][2];
    #pragma unroll
    for (int m = 0; m < 8; ++m)
        #pragma unroll
        for (int ks = 0; ks < 2; ++ks) {
            int La = (m * 16 + l15) * 128 + ks * 64 + l4 * 16;
            aoff[m][ks] = SWZ128(La);
        }
    #pragma unroll
    for (int n = 0; n < 4; ++n)
        #pragma unroll
        for (int ks = 0; ks < 2; ++ks) {
            int Lb = ((wc & 1) * 64 + n * 16 + l15) * 128 + ks * 64 + l4 * 16;
            boff[n][ks] = SWZ128(Lb);
        }

    int nt = K >> 6;                // 16
    STAGE6(0, 0);
    STAGE6(1, 1);
    for (int t = 0; t < nt; ++t) {
        int buf = t & 1;
        if (t + 1 < nt) VMW(8);
        else            VMW(0);
        __builtin_amdgcn_sched_barrier(0);
        __builtin_amdgcn_s_barrier();            // tile t fully resident
        __builtin_amdgcn_sched_barrier(0);
        const char* ab = (const char*)As[buf][wr];
        const char* bb = (const char*)Bs[buf][wc >> 1];
        bf16x8 bfr[4][2];
        #pragma unroll
        for (int n = 0; n < 4; ++n)
            #pragma unroll
            for (int ks = 0; ks < 2; ++ks)
                bfr[n][ks] = *(const bf16x8*)(bb + boff[n][ks]);
        __builtin_amdgcn_s_setprio(1);
        #pragma unroll
        for (int rh = 0; rh < 2; ++rh) {
            bf16x8 af[4][2];
            #pragma unroll
            for (int mm = 0; mm < 4; ++mm)
                #pragma unroll
                for (int ks = 0; ks < 2; ++ks)
                    af[mm][ks] = *(const bf16x8*)(ab + aoff[rh * 4 + mm][ks]);
            #pragma unroll
            for (int mm = 0; mm < 4; ++mm)
                #pragma unroll
                for (int n = 0; n < 4; ++n) {
                    acc[rh*4+mm][n] = __builtin_amdgcn_mfma_f32_16x16x32_bf16(af[mm][0], bfr[n][0], acc[rh*4+mm][n], 0, 0, 0);
                    acc[rh*4+mm][n] = __builtin_amdgcn_mfma_f32_16x16x32_bf16(af[mm][1], bfr[n][1], acc[rh*4+mm][n], 0, 0, 0);
                }
        }
        __builtin_amdgcn_s_setprio(0);
        __builtin_amdgcn_sched_barrier(0);
        __builtin_amdgcn_s_barrier();            // all waves done with buf
        __builtin_amdgcn_sched_barrier(0);
        if (t + 2 < nt) STAGE6(t + 2, buf);
    }
    #undef STAGE6

    #pragma unroll
    for (int m = 0; m < 8; ++m) {
        int row0 = bm + wr * 128 + m * 16 + l4 * 4;
        #pragma unroll
        for (int n = 0; n < 4; ++n) {
            int col = bn + wc * 64 + n * 16 + l15;
            float bb = bias[col];
            f32x4 v = acc[m][n];
            #pragma unroll
            for (int i = 0; i < 4; ++i)
                outp[(size_t)(row0 + i) * VV + col] = v[i] + bb;
        }
    }
}

// ---------------------------------------------------------------------------
// Flash attention (R9 schedule): swapped-QK^T + counted-vmcnt dbuf staging +
// defer-max. NEW: XCD-head-affine grid (xcd = bid&7 owns heads {2x,2x+1} ->
// 2 MB K/V working set per 4 MB L2; K/V HBM-fetched once, L2-hit x32 reuse),
// longest-first within each XCD.
// qg/kg [H][T][64] bf16, vt [H][64][T] bf16. x += softmax(QK^T * D^-0.5) V.
// ---------------------------------------------------------------------------
__global__ __launch_bounds__(256) void attn_kernel(
    const unsigned short* __restrict__ qg, const unsigned short* __restrict__ kg,
    const unsigned short* __restrict__ vt, float* __restrict__ x)
{
    __shared__ unsigned short Ks[2][64 * 64];   // [u][d] swizzled
    __shared__ unsigned short Vs[2][64 * 64];   // [d][u] swizzled
    __shared__ unsigned short Ps[4][16 * 64];   // per wave [q][u] swizzled
    int tid = threadIdx.x;
    int w = tid >> 6, lane = tid & 63;
    int l15 = lane & 15, l4 = lane >> 4;
    // XCD-head-affine, longest-first within XCD
    int bid = blockIdx.x;
    int j = bid >> 3;                           // 0..63 within XCD
    int hh = (bid & 7) * 2 + (j & 1);
    int qb = (31 - (j >> 1)) * 64;

    // Q as B-operand: B[n=q=l15][d = l4*8+j]
    const unsigned short* qrow = qg + ((size_t)hh * TT + qb + w * 16 + l15) * HSZ + l4 * 8;
    bf16x8 qf0 = *(const bf16x8*)(qrow);
    bf16x8 qf1 = *(const bf16x8*)(qrow + 32);

    int t16 = tid * 16;
    int lgs = SWZ128(t16);
    int surow = lgs >> 7;          // 0..31
    int subyte = lgs & 127;
    const char* kbase = (const char*)(kg + (size_t)hh * TT * HSZ);
    const char* vbase = (const char*)(vt + (size_t)hh * HSZ * TT);

    #define ASTAGE(ib, buf) do { \
        int ub_ = (ib) * 64; \
        GLL(kbase + (size_t)(ub_ + surow) * 128 + subyte,          (char*)Ks[buf] + w * 1024); \
        GLL(kbase + (size_t)(ub_ + 32 + surow) * 128 + subyte,     (char*)Ks[buf] + 4096 + w * 1024); \
        GLL(vbase + (size_t)surow * 4096 + ub_ * 2 + subyte,       (char*)Vs[buf] + w * 1024); \
        GLL(vbase + (size_t)(surow + 32) * 4096 + ub_ * 2 + subyte,(char*)Vs[buf] + 4096 + w * 1024); \
    } while (0)

    f32x4 zz = {0.f, 0.f, 0.f, 0.f};
    f32x4 o[4];
    #pragma unroll
    for (int i = 0; i < 4; ++i) o[i] = zz;
    float mrun = -INFINITY, lrun = 0.f;   // per lane: row q = l15

    const float scale = 0.03125f;  // D^-0.5
    int nkv = (qb >> 6) + 1;
    ASTAGE(0, 0);
    if (nkv > 1) ASTAGE(1, 1);
    int cur = 0;
    for (int ib = 0; ib < nkv; ++ib) {
        bool diag = (ib * 64 == qb);
        // wait this tile's 4 loads only; next tile's 4 stay in flight
        if (ib + 1 < nkv) VMW(4);
        else              VMW(0);
        __builtin_amdgcn_sched_barrier(0);
        __builtin_amdgcn_s_barrier();          // tile ib resident (all waves)
        __builtin_amdgcn_sched_barrier(0);
        const char* ksc = (const char*)Ks[cur];
        const char* vsc = (const char*)Vs[cur];

        // S^T = K Q^T : frag f covers u_loc = 16f + l4*4 + i, q = l15
        f32x4 sfr[4];
        __builtin_amdgcn_s_setprio(1);
        #pragma unroll
        for (int f = 0; f < 4; ++f) {
            int lgb = (f * 16 + l15) * 128 + l4 * 16;
            bf16x8 k0 = *(const bf16x8*)(ksc + SWZ128(lgb));
            bf16x8 k1 = *(const bf16x8*)(ksc + SWZ128(lgb + 64));
            f32x4 z = zz;
            z = __builtin_amdgcn_mfma_f32_16x16x32_bf16(k0, qf0, z, 0, 0, 0);
            z = __builtin_amdgcn_mfma_f32_16x16x32_bf16(k1, qf1, z, 0, 0, 0);
            sfr[f] = z;
        }
        __builtin_amdgcn_s_setprio(0);

        // scale + causal mask + row max (all rows parallel; row q = l15)
        float mx = -INFINITY;
        #pragma unroll
        for (int f = 0; f < 4; ++f)
            #pragma unroll
            for (int i = 0; i < 4; ++i) {
                float s = sfr[f][i] * scale;
                if (diag && (16 * f + (l4 << 2) + i) > (w * 16 + l15)) s = -INFINITY;
                sfr[f][i] = s;
                mx = fmaxf(mx, s);
            }
        mx = fmaxf(mx, __shfl_xor(mx, 16));
        mx = fmaxf(mx, __shfl_xor(mx, 32));
        // defer-max (T13): skip m-update + O-rescale unless max grew by > 8
        bool grow = __any(mx > mrun + 8.0f);
        float c = 1.0f;
        if (grow) {
            float mn = fmaxf(mrun, mx);
            c = __expf(mrun - mn);
            mrun = mn;
        }
        float ps = 0.f;
        #pragma unroll
        for (int f = 0; f < 4; ++f)
            #pragma unroll
            for (int i = 0; i < 4; ++i) {
                float p = __expf(sfr[f][i] - mrun);
                sfr[f][i] = p;
                ps += p;
            }
        ps += __shfl_xor(ps, 16);
        ps += __shfl_xor(ps, 32);
        lrun = lrun * c + ps;
        if (grow) {
            // deliver c (at lane l15=q) to output-row lanes (q=l4*4+i)
            #pragma unroll
            for (int i = 0; i < 4; ++i) {
                float ci = __shfl(c, (lane & 48) + (l4 << 2) + i);
                #pragma unroll
                for (int sf = 0; sf < 4; ++sf) o[sf][i] *= ci;
            }
        }

        // write P (bf16, packed pairs) to wave-private swizzled LDS [q][u]
        unsigned short* pw = Ps[w];
        #pragma unroll
        for (int f = 0; f < 4; ++f) {
            unsigned a0 = ((unsigned)f2bf(sfr[f][0])) | (((unsigned)f2bf(sfr[f][1])) << 16);
            unsigned a1 = ((unsigned)f2bf(sfr[f][2])) | (((unsigned)f2bf(sfr[f][3])) << 16);
            int byte0 = l15 * 128 + (16 * f + (l4 << 2)) * 2;
            *(unsigned*)((char*)pw + SWZ128(byte0)) = a0;
            *(unsigned*)((char*)pw + SWZ128(byte0 + 4)) = a1;
        }
        // O += P V   (A = P[q][u], B = V^T[d][u])
        bf16x8 pa0 = *(const bf16x8*)((const char*)pw + SWZ128(l15 * 128 + l4 * 16));
        bf16x8 pa1 = *(const bf16x8*)((const char*)pw + SWZ128(l15 * 128 + 64 + l4 * 16));
        __builtin_amdgcn_s_setprio(1);
        #pragma unroll
        for (int sf = 0; sf < 4; ++sf) {
            int lgb = (sf * 16 + l15) * 128 + l4 * 16;
            bf16x8 v0 = *(const bf16x8*)(vsc + SWZ128(lgb));
            bf16x8 v1 = *(const bf16x8*)(vsc + SWZ128(lgb + 64));
            o[sf] = __builtin_amdgcn_mfma_f32_16x16x32_bf16(pa0, v0, o[sf], 0, 0, 0);
            o[sf] = __builtin_amdgcn_mfma_f32_16x16x32_bf16(pa1, v1, o[sf], 0, 0, 0);
        }
        __builtin_amdgcn_s_setprio(0);
        __builtin_amdgcn_sched_barrier(0);
        __builtin_amdgcn_s_barrier();          // all waves done reading cur
        __builtin_amdgcn_sched_barrier(0);
        if (ib + 2 < nkv) ASTAGE(ib + 2, cur); // refill freed buffer
        cur ^= 1;
    }
    #undef ASTAGE
    float rl[4];
    #pragma unroll
    for (int i = 0; i < 4; ++i)
        rl[i] = 1.0f / __shfl(lrun, (lane & 48) + (l4 << 2) + i);
    #pragma unroll
    for (int sf = 0; sf < 4; ++sf)
        #pragma unroll
        for (int i = 0; i < 4; ++i) {
            int q = qb + w * 16 + l4 * 4 + i;
            int d = hh * HSZ + sf * 16 + l15;
            x[(size_t)q * DD + d] += o[sf][i] * rl[i];
        }
}

// ---------------------------------------------------------------------------
extern "C" void kernel_launch(void* const* d_in, const int* in_sizes, int n_in,
                              void* d_out, int out_size, void* d_ws, size_t ws_size,
                              hipStream_t stream)
{
    const int*   idx    = (const int*)  d_in[0];
    const float* tok    = (const float*)d_in[1];
    const float* pos    = (const float*)d_in[2];
    const float* ln1_g  = (const float*)d_in[3];
    const float* ln1_b  = (const float*)d_in[4];
    const float* wq     = (const float*)d_in[5];
    const float* wk     = (const float*)d_in[6];
    const float* wv     = (const float*)d_in[7];
    const float* ln2_g  = (const float*)d_in[8];
    const float* ln2_b  = (const float*)d_in[9];
    const float* w1     = (const float*)d_in[10];
    const float* b1     = (const float*)d_in[11];
    const float* w2     = (const float*)d_in[12];
    const float* b2     = (const float*)d_in[13];
    const float* lnf_g  = (const float*)d_in[14];
    const float* lnf_b  = (const float*)d_in[15];
    const float* w_un   = (const float*)d_in[16];
    const float* b_un   = (const float*)d_in[17];
    float* out = (float*)d_out;

    char* W = (char*)d_ws;
    float*          x    = (float*)(W);                          // 8 MB
    unsigned short* h    = (unsigned short*)(W + 8388608);       // 4 MB
    unsigned short* qg   = (unsigned short*)(W + 12582912);      // 4 MB
    unsigned short* kg   = (unsigned short*)(W + 16777216);      // 4 MB
    unsigned short* vt   = (unsigned short*)(W + 20971520);      // 4 MB
    float*          Pp   = (float*)(W + 8388608);                // 16 MB, aliases h/qg/kg/vt
                                                                 // (all dead during FFN2; R10/R12-verified)
    unsigned short* h1   = (unsigned short*)(W + 25165824);      // 16 MB
    unsigned short* wqkvT= (unsigned short*)(W + 41943040);      // 12.6 MB
    unsigned short* w1T  = (unsigned short*)(W + 54525952);      // 16.8 MB
    unsigned short* w2T  = (unsigned short*)(W + 71303168);      // 16.8 MB
    unsigned short* wunT = (unsigned short*)(W + 88080384);      // 65.5 MB -> 153.6 MB total
    (void)kg; (void)ws_size; (void)in_sizes; (void)n_in; (void)out_size;

    // weight conversion (per call; ~370 MB traffic)
    qkv_tcast<<<dim3(16, 48, 2), 256, 0, stream>>>(wq, wk, wv, wqkvT);
    tcast<<<dim3(64, 16, 2), 256, 0, stream>>>(w1, w1T, DD, FFD, (size_t)DD * FFD, (size_t)DD * FFD);
    tcast<<<dim3(16, 64, 2), 256, 0, stream>>>(w2, w2T, FFD, DD, (size_t)FFD * DD, (size_t)FFD * DD);
    tcast<<<dim3(500, 16, 1), 256, 0, stream>>>(w_un, wunT, DD, VV, 0, 0);

    // embed + LN1(l=0) fused
    embed_ln<<<TT, 256, 0, stream>>>(idx, tok, pos, ln1_g, ln1_b, x, h);

    for (int l = 0; l < NL; ++l) {
        // (h already holds LN1 output: from embed_ln for l=0, from fused
        //  ffn2_reduce_ln for l=1)
        mgemm<0, 64><<<dim3(48, 16), 256, 0, stream>>>(h, wqkvT + (size_t)l * 3072 * DD, nullptr, qg, TT, 3072, DD, DD);
        attn_kernel<<<512, 256, 0, stream>>>(qg, kg, vt, x);
        ln_kernel<<<TT, 256, 0, stream>>>(x, ln2_g + l * DD, ln2_b + l * DD, h);
        mgemm<1, 128><<<dim3(32, 16), 256, 0, stream>>>(h, w1T + (size_t)l * FFD * DD, b1 + (size_t)l * FFD, h1, TT, FFD, DD, DD);
        // FFN2 split-K=2: partials (z-planes) then fused reduce + next LN
        mgemm<3, 64><<<dim3(16, 16, 2), 256, 0, stream>>>(h1, w2T + (size_t)l * DD * FFD, nullptr, Pp, TT, DD, FFD / 2, FFD);
        const float* ng = (l + 1 < NL) ? (ln1_g + (l + 1) * DD) : lnf_g;
        const float* nb = (l + 1 < NL) ? (ln1_b + (l + 1) * DD) : lnf_b;
        ffn2_reduce_ln<<<TT, 256, 0, stream>>>(Pp, b2 + (size_t)l * DD, x, ng, nb, h);
    }

    // h holds LN_f(x); unembed
    mgemm256<<<dim3(1024), 512, 0, stream>>>(h, wunT, b_un, out, TT, VV, DD);
}

// Round 14
// 592.824 us; speedup vs baseline: 1.2077x; 1.0119x over previous
//
#include <hip/hip_runtime.h>
#include <hip/hip_bf16.h>

#define TT 2048
#define DD 1024
#define NH 16
#define HSZ 64
#define FFD 4096
#define VV 32000
#define NL 2

typedef __bf16 bf16x8 __attribute__((ext_vector_type(8)));
typedef float f32x4 __attribute__((ext_vector_type(4)));

__device__ __forceinline__ unsigned short f2bf(float f) {
    unsigned int u = __float_as_uint(f);
    return (unsigned short)((u + 0x7FFFu + ((u >> 16) & 1u)) >> 16);
}

// async global->LDS, 16B per lane; lds dst is wave-uniform base + lane*16
#define GLL(gsrc, ldst) \
  __builtin_amdgcn_global_load_lds((const __attribute__((address_space(1))) void*)(gsrc), \
                                   (__attribute__((address_space(3))) void*)(ldst), 16, 0, 0)

// XOR swizzles (involutions: XOR bits are disjoint from their key bits)
#define SWZ64(L)  ((L) ^ ((((L) >> 7) & 3) << 4))   // 64B-row tiles (GEMM As/Bs)
#define SWZ128(L) ((L) ^ ((((L) >> 7) & 7) << 4))   // 128B-row tiles (attn K + 256q gemm)
#define SWZ256(L) ((L) ^ ((((L) >> 8) & 7) << 4))   // 256B-row tiles (attn V/P, KVBLK=128)

#define VMW(n) asm volatile("s_waitcnt vmcnt(" #n ")" ::: "memory")

// ---------------------------------------------------------------------------
// Embedding fused with LN1(layer0): block = row t; writes x (fp32) and h (bf16)
// ---------------------------------------------------------------------------
__global__ __launch_bounds__(256) void embed_ln(
    const int* __restrict__ idx, const float* __restrict__ tok,
    const float* __restrict__ pos, const float* __restrict__ g,
    const float* __restrict__ b, float* __restrict__ x,
    unsigned short* __restrict__ h)
{
    int t = blockIdx.x;
    int tid = threadIdx.x;
    int d4 = tid * 4;
    int token = idx[t];
    float4 a = *(const float4*)&tok[(size_t)token * DD + d4];
    float4 p = *(const float4*)&pos[(size_t)t * DD + d4];
    float4 xv;
    xv.x = a.x + p.x; xv.y = a.y + p.y; xv.z = a.z + p.z; xv.w = a.w + p.w;
    *(float4*)&x[(size_t)t * DD + d4] = xv;
    float s  = xv.x + xv.y + xv.z + xv.w;
    float s2 = xv.x*xv.x + xv.y*xv.y + xv.z*xv.z + xv.w*xv.w;
    #pragma unroll
    for (int off = 32; off >= 1; off >>= 1) {
        s  += __shfl_xor(s,  off);
        s2 += __shfl_xor(s2, off);
    }
    __shared__ float ls[4], ls2[4];
    int w = tid >> 6;
    if ((tid & 63) == 0) { ls[w] = s; ls2[w] = s2; }
    __syncthreads();
    float sum  = ls[0] + ls[1] + ls[2] + ls[3];
    float sum2 = ls2[0] + ls2[1] + ls2[2] + ls2[3];
    float mean = sum * (1.0f / DD);
    float var  = sum2 * (1.0f / DD) - mean * mean;
    float r = rsqrtf(var + 1e-5f);
    float4 gv = *(const float4*)&g[d4];
    float4 bv = *(const float4*)&b[d4];
    ushort4 pk;
    pk.x = f2bf((xv.x - mean) * r * gv.x + bv.x);
    pk.y = f2bf((xv.y - mean) * r * gv.y + bv.y);
    pk.z = f2bf((xv.z - mean) * r * gv.z + bv.z);
    pk.w = f2bf((xv.w - mean) * r * gv.w + bv.w);
    *(ushort4*)&h[(size_t)t * DD + d4] = pk;
}

// LayerNorm fp32 -> bf16 out (used for ln2)
__global__ __launch_bounds__(256) void ln_kernel(
    const float* __restrict__ x, const float* __restrict__ g,
    const float* __restrict__ b, unsigned short* __restrict__ out)
{
    int t = blockIdx.x;
    int tid = threadIdx.x;
    int d4 = tid * 4;
    float4 xv = *(const float4*)&x[(size_t)t * DD + d4];
    float s  = xv.x + xv.y + xv.z + xv.w;
    float s2 = xv.x*xv.x + xv.y*xv.y + xv.z*xv.z + xv.w*xv.w;
    #pragma unroll
    for (int off = 32; off >= 1; off >>= 1) {
        s  += __shfl_xor(s,  off);
        s2 += __shfl_xor(s2, off);
    }
    __shared__ float ls[4], ls2[4];
    int w = tid >> 6;
    if ((tid & 63) == 0) { ls[w] = s; ls2[w] = s2; }
    __syncthreads();
    float sum  = ls[0] + ls[1] + ls[2] + ls[3];
    float sum2 = ls2[0] + ls2[1] + ls2[2] + ls2[3];
    float mean = sum * (1.0f / DD);
    float var  = sum2 * (1.0f / DD) - mean * mean;
    float r = rsqrtf(var + 1e-5f);
    float4 gv = *(const float4*)&g[d4];
    float4 bv = *(const float4*)&b[d4];
    ushort4 pk;
    pk.x = f2bf((xv.x - mean) * r * gv.x + bv.x);
    pk.y = f2bf((xv.y - mean) * r * gv.y + bv.y);
    pk.z = f2bf((xv.z - mean) * r * gv.z + bv.z);
    pk.w = f2bf((xv.w - mean) * r * gv.w + bv.w);
    *(ushort4*)&out[(size_t)t * DD + d4] = pk;
}

// generic cast+transpose: src [R][C] f32 -> dst [C][R] bf16
__global__ __launch_bounds__(256) void tcast(
    const float* __restrict__ src, unsigned short* __restrict__ dst,
    int R, int C, size_t sstride, size_t dstride)
{
    __shared__ float tile[64][65];
    const float* s = src + (size_t)blockIdx.z * sstride;
    unsigned short* d = dst + (size_t)blockIdx.z * dstride;
    int c0 = blockIdx.x * 64, r0 = blockIdx.y * 64;
    #pragma unroll
    for (int i = 0; i < 16; ++i) {
        int id = i * 256 + threadIdx.x;
        int rr = id >> 6, cc = id & 63;
        tile[rr][cc] = s[(size_t)(r0 + rr) * C + (c0 + cc)];
    }
    __syncthreads();
    #pragma unroll
    for (int i = 0; i < 16; ++i) {
        int id = i * 256 + threadIdx.x;
        int cc = id >> 6, rr = id & 63;
        d[(size_t)(c0 + cc) * R + (r0 + rr)] = f2bf(tile[rr][cc]);
    }
}

// wq/wk/wv [L][H][D][HS] f32 -> wqkvT [L][3072][1024] bf16 (row n = mat*1024+h*64+s, col c)
__global__ __launch_bounds__(256) void qkv_tcast(
    const float* __restrict__ wq, const float* __restrict__ wk,
    const float* __restrict__ wv, unsigned short* __restrict__ dst)
{
    __shared__ float tile[64][65];
    int l = blockIdx.z;
    int mat = blockIdx.y >> 4, hh = blockIdx.y & 15;
    const float* s = (mat == 0) ? wq : (mat == 1) ? wk : wv;
    s += (((size_t)l * NH + hh) * DD) * HSZ;   // [1024][64]
    int r0 = blockIdx.x * 64;
    #pragma unroll
    for (int i = 0; i < 16; ++i) {
        int id = i * 256 + threadIdx.x;
        int rr = id >> 6, cc = id & 63;
        tile[rr][cc] = s[(size_t)(r0 + rr) * HSZ + cc];
    }
    __syncthreads();
    unsigned short* d = dst + (size_t)l * 3072 * DD + ((size_t)mat * DD + hh * HSZ) * DD;
    #pragma unroll
    for (int i = 0; i < 16; ++i) {
        int id = i * 256 + threadIdx.x;
        int cc = id >> 6, rr = id & 63;
        d[(size_t)cc * DD + (r0 + rr)] = f2bf(tile[rr][cc]);
    }
}

// ---------------------------------------------------------------------------
// bf16 MFMA GEMM: C = A[M,Kst](K cols used) * Bt[N,Kst]^T, 128xBN tile,
// BK=32, 4 waves, ring-3 K-tile buffers + counted vmcnt.
// EPI 0: QKV split. EPI 1: bf16 relu(acc+bias). EPI 2: fp32 += acc+bias.
// EPI 3: split-K partial (blockIdx.z selects K-half; fp32 plain write).
// ---------------------------------------------------------------------------
template<int EPI, int BN>
__global__ __launch_bounds__(256) void mgemm(
    const unsigned short* __restrict__ A, const unsigned short* __restrict__ Bt,
    const float* __restrict__ bias, void* __restrict__ outp,
    int M, int N, int K, int Kst)
{
    constexpr int FN = BN / 64 * 2;            // n-frags per wave: 4 or 2
    __shared__ unsigned short As[3][128 * 32];
    __shared__ unsigned short Bs[3][BN * 32];
    int tid = threadIdx.x;
    int w = tid >> 6, lane = tid & 63;
    int l15 = lane & 15, l4 = lane >> 4;
    int bm = blockIdx.y * 128, bn = blockIdx.x * BN;
    int wr = (w >> 1) * 64, wc = (w & 1) * (BN / 2);
    if (EPI == 3) {
        int z = blockIdx.z;                    // K-half: offset A/Bt cols, outp plane
        A  += (size_t)z * K;
        Bt += (size_t)z * K;
        outp = (float*)outp + (size_t)z * TT * DD;
    }

    f32x4 zz = {0.f, 0.f, 0.f, 0.f};
    f32x4 acc[4][FN];
    #pragma unroll
    for (int m = 0; m < 4; ++m)
        #pragma unroll
        for (int n = 0; n < FN; ++n) acc[m][n] = zz;

    int t16 = tid * 16;
    int lg = SWZ64(t16);
    int srow = lg >> 6;            // 0..63
    int skel = (lg & 63) >> 1;     // k element offset, multiple of 8
    const unsigned short* aS0 = A + (size_t)(bm + srow) * Kst + skel;
    const unsigned short* aS1 = A + (size_t)(bm + 64 + srow) * Kst + skel;
    const unsigned short* bS0 = Bt + (size_t)(bn + srow) * Kst + skel;
    const unsigned short* bS1 = Bt + (size_t)(bn + 64 + srow) * Kst + skel;

    #define STAGE(t, slot) do { int kk_ = (t) * 32; \
        GLL(aS0 + kk_, (char*)As[slot] + w * 1024); \
        GLL(aS1 + kk_, (char*)As[slot] + 4096 + w * 1024); \
        GLL(bS0 + kk_, (char*)Bs[slot] + w * 1024); \
        if (BN == 128) GLL(bS1 + kk_, (char*)Bs[slot] + 4096 + w * 1024); } while (0)

    int aoff[4], boff[FN];
    #pragma unroll
    for (int m = 0; m < 4; ++m)
        aoff[m] = SWZ64((wr + m * 16 + l15) * 64 + l4 * 16);
    #pragma unroll
    for (int n = 0; n < FN; ++n)
        boff[n] = SWZ64((wc + n * 16 + l15) * 64 + l4 * 16);

    int nt = K >> 5;
    STAGE(0, 0);
    STAGE(1, 1);
    STAGE(2, 2);
    int slot = 0;
    for (int t = 0; t < nt; ++t) {
        if (BN == 128) {
            if (t + 2 < nt)      VMW(8);
            else if (t + 1 < nt) VMW(4);
            else                 VMW(0);
        } else {
            if (t + 2 < nt)      VMW(6);
            else if (t + 1 < nt) VMW(3);
            else                 VMW(0);
        }
        __builtin_amdgcn_sched_barrier(0);
        __builtin_amdgcn_s_barrier();          // all waves: tile t resident
        __builtin_amdgcn_sched_barrier(0);
        bf16x8 af[4], bfr[FN];
        #pragma unroll
        for (int m = 0; m < 4; ++m) af[m] = *(const bf16x8*)((const char*)As[slot] + aoff[m]);
        #pragma unroll
        for (int n = 0; n < FN; ++n) bfr[n] = *(const bf16x8*)((const char*)Bs[slot] + boff[n]);
        #pragma unroll
        for (int m = 0; m < 4; ++m)
            #pragma unroll
            for (int n = 0; n < FN; ++n)
                acc[m][n] = __builtin_amdgcn_mfma_f32_16x16x32_bf16(af[m], bfr[n], acc[m][n], 0, 0, 0);
        __builtin_amdgcn_sched_barrier(0);
        __builtin_amdgcn_s_barrier();          // all waves done reading slot
        __builtin_amdgcn_sched_barrier(0);
        if (t + 3 < nt) STAGE(t + 3, slot);    // refill freed slot
        slot = (slot == 2) ? 0 : slot + 1;
    }
    #undef STAGE

    #pragma unroll
    for (int m = 0; m < 4; ++m) {
        int row0 = bm + wr + m * 16 + l4 * 4;
        #pragma unroll
        for (int n = 0; n < FN; ++n) {
            int col = bn + wc + n * 16 + l15;
            f32x4 v = acc[m][n];
            if (EPI == 0) {
                int mat = col >> 10, hh = (col >> 6) & 15, ss = col & 63;
                unsigned short* base = (unsigned short*)outp + (size_t)mat * ((size_t)NH * TT * HSZ);
                if (mat < 2) {
                    #pragma unroll
                    for (int i = 0; i < 4; ++i)
                        base[((size_t)hh * TT + row0 + i) * HSZ + ss] = f2bf(v[i]);
                } else {
                    ushort4 pk;
                    pk.x = f2bf(v[0]); pk.y = f2bf(v[1]); pk.z = f2bf(v[2]); pk.w = f2bf(v[3]);
                    *(ushort4*)&base[((size_t)hh * HSZ + ss) * TT + row0] = pk;
                }
            } else if (EPI == 1) {
                float bb = bias[col];
                unsigned short* o = (unsigned short*)outp;
                #pragma unroll
                for (int i = 0; i < 4; ++i)
                    o[(size_t)(row0 + i) * FFD + col] = f2bf(fmaxf(v[i] + bb, 0.f));
            } else if (EPI == 2) {
                float bb = bias[col];
                float* xx = (float*)outp;
                #pragma unroll
                for (int i = 0; i < 4; ++i)
                    xx[(size_t)(row0 + i) * DD + col] += v[i] + bb;
            } else {
                float* xx = (float*)outp;
                #pragma unroll
                for (int i = 0; i < 4; ++i)
                    xx[(size_t)(row0 + i) * DD + col] = v[i];
            }
        }
    }
}

// FFN2 split-K reduce fused with following LN:
// block = row t. x += P0 + P1 + b2 (write x), then h = LN(x; g, b) bf16.
__global__ __launch_bounds__(256) void ffn2_reduce_ln(
    const float* __restrict__ P, const float* __restrict__ b2,
    float* __restrict__ x, const float* __restrict__ g,
    const float* __restrict__ b, unsigned short* __restrict__ h)
{
    int t = blockIdx.x;
    int tid = threadIdx.x;
    int d4 = tid * 4;
    size_t o = (size_t)t * DD + d4;
    float4 p0 = *(const float4*)&P[o];
    float4 p1 = *(const float4*)&P[o + (size_t)TT * DD];
    float4 bb = *(const float4*)&b2[d4];
    float4 xv = *(float4*)&x[o];
    xv.x += p0.x + p1.x + bb.x;
    xv.y += p0.y + p1.y + bb.y;
    xv.z += p0.z + p1.z + bb.z;
    xv.w += p0.w + p1.w + bb.w;
    *(float4*)&x[o] = xv;
    float s  = xv.x + xv.y + xv.z + xv.w;
    float s2 = xv.x*xv.x + xv.y*xv.y + xv.z*xv.z + xv.w*xv.w;
    #pragma unroll
    for (int off = 32; off >= 1; off >>= 1) {
        s  += __shfl_xor(s,  off);
        s2 += __shfl_xor(s2, off);
    }
    __shared__ float ls[4], ls2[4];
    int w = tid >> 6;
    if ((tid & 63) == 0) { ls[w] = s; ls2[w] = s2; }
    __syncthreads();
    float sum  = ls[0] + ls[1] + ls[2] + ls[3];
    float sum2 = ls2[0] + ls2[1] + ls2[2] + ls2[3];
    float mean = sum * (1.0f / DD);
    float var  = sum2 * (1.0f / DD) - mean * mean;
    float r = rsqrtf(var + 1e-5f);
    float4 gv = *(const float4*)&g[d4];
    float4 bv = *(const float4*)&b[d4];
    ushort4 pk;
    pk.x = f2bf((xv.x - mean) * r * gv.x + bv.x);
    pk.y = f2bf((xv.y - mean) * r * gv.y + bv.y);
    pk.z = f2bf((xv.z - mean) * r * gv.z + bv.z);
    pk.w = f2bf((xv.w - mean) * r * gv.w + bv.w);
    *(ushort4*)&h[o] = pk;
}

// ---------------------------------------------------------------------------
// 256x256 / BK=64 / 8-wave GEMM for the unembed (C = A * Bt^T, fp32 out+bias).
// R5 version (measured ~186 us): 2 K-tile dbuf (128 KiB LDS), counted
// vmcnt(8), 2 barriers per K-tile, setprio around MFMA, XCD-grouped grid.
// ---------------------------------------------------------------------------
__global__ __launch_bounds__(512, 2) void mgemm256(
    const unsigned short* __restrict__ A, const unsigned short* __restrict__ Bt,
    const float* __restrict__ bias, float* __restrict__ outp,
    int M, int N, int K)
{
    __shared__ unsigned short As[2][2][128 * 64];   // [dbuf][half][row*64k]
    __shared__ unsigned short Bs[2][2][128 * 64];
    int tid = threadIdx.x;
    int w = tid >> 6, lane = tid & 63;
    int l15 = lane & 15, l4 = lane >> 4;
    int wr = w >> 2, wc = w & 3;                    // wave grid 2M x 4N
    int bid = blockIdx.x;
    int xcd = bid & 7, j = bid >> 3;                // j 0..127
    int mt = j & 7, p = xcd * 16 + (j >> 3);
    if (p >= N / 256) return;                       // pad blocks exit whole
    int bm = mt * 256, bn = p * 256;

    f32x4 zz = {0.f, 0.f, 0.f, 0.f};
    f32x4 acc[8][4];
    #pragma unroll
    for (int m = 0; m < 8; ++m)
        #pragma unroll
        for (int n = 0; n < 4; ++n) acc[m][n] = zz;

    int L0 = w * 1024 + lane * 16;
    int Ls = SWZ128(L0);
    int srow = Ls >> 7;             // 0..63
    int skel = (Ls & 127) >> 1;     // k elem offset, multiple of 8
    const unsigned short* aS[2], *bS[2];
    aS[0] = A + (size_t)(bm + srow) * K + skel;
    aS[1] = A + (size_t)(bm + 128 + srow) * K + skel;
    bS[0] = Bt + (size_t)(bn + srow) * K + skel;
    bS[1] = Bt + (size_t)(bn + 128 + srow) * K + skel;
    size_t g1 = (size_t)64 * K;     // g=1: +64 rows, same skel (+8192 in LDS)

    #define STAGE6(t, buf) do { int kk_ = (t) * 64; \
        GLL(aS[0] + kk_,      (char*)As[buf][0] + w * 1024); \
        GLL(aS[0] + g1 + kk_, (char*)As[buf][0] + 8192 + w * 1024); \
        GLL(aS[1] + kk_,      (char*)As[buf][1] + w * 1024); \
        GLL(aS[1] + g1 + kk_, (char*)As[buf][1] + 8192 + w * 1024); \
        GLL(bS[0] + kk_,      (char*)Bs[buf][0] + w * 1024); \
        GLL(bS[0] + g1 + kk_, (char*)Bs[buf][0] + 8192 + w * 1024); \
        GLL(bS[1] + kk_,      (char*)Bs[buf][1] + w * 1024); \
        GLL(bS[1] + g1 + kk_, (char*)Bs[buf][1] + 8192 + w * 1024); } while (0)

    int aoff[8][2], boff[4][2];
    #pragma unroll
    for (int m = 0; m < 8; ++m)
        #pragma unroll
        for (int ks = 0; ks < 2; ++ks) {
            int La = (m * 16 + l15) * 128 + ks * 64 + l4 * 16;
            aoff[m][ks] = SWZ128(La);
        }
    #pragma unroll
    for (int n = 0; n < 4; ++n)
        #pragma unroll
        for (int ks = 0; ks < 2; ++ks) {
            int Lb = ((wc & 1) * 64 + n * 16 + l15) * 128 + ks * 64 + l4 * 16;
            boff[n][ks] = SWZ128(Lb);
        }

    int nt = K >> 6;                // 16
    STAGE6(0, 0);
    STAGE6(1, 1);
    for (int t = 0; t < nt; ++t) {
        int buf = t & 1;
        if (t + 1 < nt) VMW(8);
        else            VMW(0);
        __builtin_amdgcn_sched_barrier(0);
        __builtin_amdgcn_s_barrier();            // tile t fully resident
        __builtin_amdgcn_sched_barrier(0);
        const char* ab = (const char*)As[buf][wr];
        const char* bb = (const char*)Bs[buf][wc >> 1];
        bf16x8 bfr[4][2];
        #pragma unroll
        for (int n = 0; n < 4; ++n)
            #pragma unroll
            for (int ks = 0; ks < 2; ++ks)
                bfr[n][ks] = *(const bf16x8*)(bb + boff[n][ks]);
        __builtin_amdgcn_s_setprio(1);
        #pragma unroll
        for (int rh = 0; rh < 2; ++rh) {
            bf16x8 af[4][2];
            #pragma unroll
            for (int mm = 0; mm < 4; ++mm)
                #pragma unroll
                for (int ks = 0; ks < 2; ++ks)
                    af[mm][ks] = *(const bf16x8*)(ab + aoff[rh * 4 + mm][ks]);
            #pragma unroll
            for (int mm = 0; mm < 4; ++mm)
                #pragma unroll
                for (int n = 0; n < 4; ++n) {
                    acc[rh*4+mm][n] = __builtin_amdgcn_mfma_f32_16x16x32_bf16(af[mm][0], bfr[n][0], acc[rh*4+mm][n], 0, 0, 0);
                    acc[rh*4+mm][n] = __builtin_amdgcn_mfma_f32_16x16x32_bf16(af[mm][1], bfr[n][1], acc[rh*4+mm][n], 0, 0, 0);
                }
        }
        __builtin_amdgcn_s_setprio(0);
        __builtin_amdgcn_sched_barrier(0);
        __builtin_amdgcn_s_barrier();            // all waves done with buf
        __builtin_amdgcn_sched_barrier(0);
        if (t + 2 < nt) STAGE6(t + 2, buf);
    }
    #undef STAGE6

    #pragma unroll
    for (int m = 0; m < 8; ++m) {
        int row0 = bm + wr * 128 + m * 16 + l4 * 4;
        #pragma unroll
        for (int n = 0; n < 4; ++n) {
            int col = bn + wc * 64 + n * 16 + l15;
            float bb = bias[col];
            f32x4 v = acc[m][n];
            #pragma unroll
            for (int i = 0; i < 4; ++i)
                outp[(size_t)(row0 + i) * VV + col] = v[i] + bb;
        }
    }
}

// ---------------------------------------------------------------------------
// Flash attention, KVBLK=128: swapped-QK^T + counted-vmcnt dbuf + defer-max +
// XCD-head-affine grid. Halved per-key barrier/waitcnt/loop overhead vs
// KVBLK=64; LDS 80 KB -> 2 blocks/CU (= what the 512-block grid gives anyway).
// qg/kg [H][T][64] bf16, vt [H][64][T] bf16. x += softmax(QK^T * D^-0.5) V.
// ---------------------------------------------------------------------------
__global__ __launch_bounds__(256) void attn_kernel(
    const unsigned short* __restrict__ qg, const unsigned short* __restrict__ kg,
    const unsigned short* __restrict__ vt, float* __restrict__ x)
{
    __shared__ unsigned short Ks[2][128 * 64];  // [u][d], 128B rows, SWZ128
    __shared__ unsigned short Vs[2][64 * 128];  // [d][u], 256B rows, SWZ256
    __shared__ unsigned short Ps[4][16 * 128];  // per wave [q][u], 256B rows, SWZ256
    int tid = threadIdx.x;
    int w = tid >> 6, lane = tid & 63;
    int l15 = lane & 15, l4 = lane >> 4;
    // XCD-head-affine, longest-first within XCD
    int bid = blockIdx.x;
    int j = bid >> 3;                           // 0..63 within XCD
    int hh = (bid & 7) * 2 + (j & 1);
    int qb = (31 - (j >> 1)) * 64;

    // Q as B-operand: B[n=q=l15][d = l4*8+jj]
    const unsigned short* qrow = qg + ((size_t)hh * TT + qb + w * 16 + l15) * HSZ + l4 * 8;
    bf16x8 qf0 = *(const bf16x8*)(qrow);
    bf16x8 qf1 = *(const bf16x8*)(qrow + 32);

    // staging maps (per 4 KB GLL unit; linear dest tid*16, inverse-swz source)
    int Lu = tid * 16;
    int Lk = SWZ128(Lu);
    int kr = Lk >> 7, kb = Lk & 127;            // K: 32 rows x 128B per unit
    int Lv = SWZ256(Lu);
    int vr = Lv >> 8, vb = Lv & 255;            // V: 16 rows x 256B per unit
    const char* kbase = (const char*)(kg + (size_t)hh * TT * HSZ);
    const char* vbase = (const char*)(vt + (size_t)hh * HSZ * TT);

    #define ASTAGE(ib, buf) do { \
        int ub_ = (ib) * 128; \
        _Pragma("unroll") \
        for (int g_ = 0; g_ < 4; ++g_) \
            GLL(kbase + (size_t)(ub_ + g_ * 32 + kr) * 128 + kb, \
                (char*)Ks[buf] + g_ * 4096 + tid * 16); \
        _Pragma("unroll") \
        for (int g_ = 0; g_ < 4; ++g_) \
            GLL(vbase + (size_t)(g_ * 16 + vr) * (TT * 2) + (size_t)ub_ * 2 + vb, \
                (char*)Vs[buf] + g_ * 4096 + tid * 16); \
    } while (0)

    f32x4 zz = {0.f, 0.f, 0.f, 0.f};
    f32x4 o[4];
    #pragma unroll
    for (int i = 0; i < 4; ++i) o[i] = zz;
    float mrun = -INFINITY, lrun = 0.f;   // per lane: row q = l15

    const float scale = 0.03125f;  // D^-0.5
    int nkv = (qb >> 7) + 1;
    ASTAGE(0, 0);
    if (nkv > 1) ASTAGE(1, 1);
    int cur = 0;
    for (int ib = 0; ib < nkv; ++ib) {
        int ub = ib * 128;
        bool diag = (ub + 128 > qb);
        // wait this tile's 8 loads only; next tile's 8 stay in flight
        if (ib + 1 < nkv) VMW(8);
        else              VMW(0);
        __builtin_amdgcn_sched_barrier(0);
        __builtin_amdgcn_s_barrier();          // tile ib resident (all waves)
        __builtin_amdgcn_sched_barrier(0);
        const char* ksc = (const char*)Ks[cur];
        const char* vsc = (const char*)Vs[cur];

        // S^T = K Q^T : frag f covers u_loc = 16f + 4*l4 + i, q = l15
        f32x4 sfr[8];
        __builtin_amdgcn_s_setprio(1);
        #pragma unroll
        for (int f = 0; f < 8; ++f) {
            int lgb = (f * 16 + l15) * 128 + l4 * 16;
            bf16x8 k0 = *(const bf16x8*)(ksc + SWZ128(lgb));
            bf16x8 k1 = *(const bf16x8*)(ksc + SWZ128(lgb + 64));
            f32x4 z = zz;
            z = __builtin_amdgcn_mfma_f32_16x16x32_bf16(k0, qf0, z, 0, 0, 0);
            z = __builtin_amdgcn_mfma_f32_16x16x32_bf16(k1, qf1, z, 0, 0, 0);
            sfr[f] = z;
        }
        __builtin_amdgcn_s_setprio(0);

        // scale + causal mask + row max (all rows parallel; row q = l15)
        int qrel = qb - ub + w * 16 + l15;
        float mx = -INFINITY;
        #pragma unroll
        for (int f = 0; f < 8; ++f)
            #pragma unroll
            for (int i = 0; i < 4; ++i) {
                float s = sfr[f][i] * scale;
                if (diag && (16 * f + (l4 << 2) + i) > qrel) s = -INFINITY;
                sfr[f][i] = s;
                mx = fmaxf(mx, s);
            }
        mx = fmaxf(mx, __shfl_xor(mx, 16));
        mx = fmaxf(mx, __shfl_xor(mx, 32));
        // defer-max (T13): skip m-update + O-rescale unless max grew by > 8
        bool grow = __any(mx > mrun + 8.0f);
        float c = 1.0f;
        if (grow) {
            float mn = fmaxf(mrun, mx);
            c = __expf(mrun - mn);
            mrun = mn;
        }
        float ps = 0.f;
        #pragma unroll
        for (int f = 0; f < 8; ++f)
            #pragma unroll
            for (int i = 0; i < 4; ++i) {
                float p = __expf(sfr[f][i] - mrun);
                sfr[f][i] = p;
                ps += p;
            }
        ps += __shfl_xor(ps, 16);
        ps += __shfl_xor(ps, 32);
        lrun = lrun * c + ps;
        if (grow) {
            // deliver c (at lane l15=q) to output-row lanes (q=l4*4+i)
            #pragma unroll
            for (int i = 0; i < 4; ++i) {
                float ci = __shfl(c, (lane & 48) + (l4 << 2) + i);
                #pragma unroll
                for (int sf = 0; sf < 4; ++sf) o[sf][i] *= ci;
            }
        }

        // write P (bf16, packed pairs) to wave-private swizzled LDS [q][u]
        unsigned short* pw = Ps[w];
        #pragma unroll
        for (int f = 0; f < 8; ++f) {
            unsigned a0 = ((unsigned)f2bf(sfr[f][0])) | (((unsigned)f2bf(sfr[f][1])) << 16);
            unsigned a1 = ((unsigned)f2bf(sfr[f][2])) | (((unsigned)f2bf(sfr[f][3])) << 16);
            int byte0 = l15 * 256 + f * 32 + l4 * 8;
            *(unsigned*)((char*)pw + SWZ256(byte0)) = a0;
            *(unsigned*)((char*)pw + SWZ256(byte0 + 4)) = a1;
        }
        // O += P V   (A = P[q][u] ks-slices, B = V^T[d][u])
        bf16x8 pa[4];
        #pragma unroll
        for (int ks = 0; ks < 4; ++ks)
            pa[ks] = *(const bf16x8*)((const char*)pw + SWZ256(l15 * 256 + ks * 64 + l4 * 16));
        __builtin_amdgcn_s_setprio(1);
        #pragma unroll
        for (int sf = 0; sf < 4; ++sf) {
            f32x4 a = o[sf];
            #pragma unroll
            for (int ks = 0; ks < 4; ++ks) {
                bf16x8 v = *(const bf16x8*)(vsc + SWZ256((sf * 16 + l15) * 256 + ks * 64 + l4 * 16));
                a = __builtin_amdgcn_mfma_f32_16x16x32_bf16(pa[ks], v, a, 0, 0, 0);
            }
            o[sf] = a;
        }
        __builtin_amdgcn_s_setprio(0);
        __builtin_amdgcn_sched_barrier(0);
        __builtin_amdgcn_s_barrier();          // all waves done reading cur
        __builtin_amdgcn_sched_barrier(0);
        if (ib + 2 < nkv) ASTAGE(ib + 2, cur); // refill freed buffer
        cur ^= 1;
    }
    #undef ASTAGE
    float rl[4];
    #pragma unroll
    for (int i = 0; i < 4; ++i)
        rl[i] = 1.0f / __shfl(lrun, (lane & 48) + (l4 << 2) + i);
    #pragma unroll
    for (int sf = 0; sf < 4; ++sf)
        #pragma unroll
        for (int i = 0; i < 4; ++i) {
            int q = qb + w * 16 + l4 * 4 + i;
            int d = hh * HSZ + sf * 16 + l15;
            x[(size_t)q * DD + d] += o[sf][i] * rl[i];
        }
}

// ---------------------------------------------------------------------------
extern "C" void kernel_launch(void* const* d_in, const int* in_sizes, int n_in,
                              void* d_out, int out_size, void* d_ws, size_t ws_size,
                              hipStream_t stream)
{
    const int*   idx    = (const int*)  d_in[0];
    const float* tok    = (const float*)d_in[1];
    const float* pos    = (const float*)d_in[2];
    const float* ln1_g  = (const float*)d_in[3];
    const float* ln1_b  = (const float*)d_in[4];
    const float* wq     = (const float*)d_in[5];
    const float* wk     = (const float*)d_in[6];
    const float* wv     = (const float*)d_in[7];
    const float* ln2_g  = (const float*)d_in[8];
    const float* ln2_b  = (const float*)d_in[9];
    const float* w1     = (const float*)d_in[10];
    const float* b1     = (const float*)d_in[11];
    const float* w2     = (const float*)d_in[12];
    const float* b2     = (const float*)d_in[13];
    const float* lnf_g  = (const float*)d_in[14];
    const float* lnf_b  = (const float*)d_in[15];
    const float* w_un   = (const float*)d_in[16];
    const float* b_un   = (const float*)d_in[17];
    float* out = (float*)d_out;

    char* W = (char*)d_ws;
    float*          x    = (float*)(W);                          // 8 MB
    unsigned short* h    = (unsigned short*)(W + 8388608);       // 4 MB
    unsigned short* qg   = (unsigned short*)(W + 12582912);      // 4 MB
    unsigned short* kg   = (unsigned short*)(W + 16777216);      // 4 MB
    unsigned short* vt   = (unsigned short*)(W + 20971520);      // 4 MB
    float*          Pp   = (float*)(W + 8388608);                // 16 MB, aliases h/qg/kg/vt
                                                                 // (all dead during FFN2; R12/R13-verified)
    unsigned short* h1   = (unsigned short*)(W + 25165824);      // 16 MB
    unsigned short* wqkvT= (unsigned short*)(W + 41943040);      // 12.6 MB
    unsigned short* w1T  = (unsigned short*)(W + 54525952);      // 16.8 MB
    unsigned short* w2T  = (unsigned short*)(W + 71303168);      // 16.8 MB
    unsigned short* wunT = (unsigned short*)(W + 88080384);      // 65.5 MB -> 153.6 MB total
    (void)kg; (void)ws_size; (void)in_sizes; (void)n_in; (void)out_size;

    // weight conversion (per call; ~370 MB traffic)
    qkv_tcast<<<dim3(16, 48, 2), 256, 0, stream>>>(wq, wk, wv, wqkvT);
    tcast<<<dim3(64, 16, 2), 256, 0, stream>>>(w1, w1T, DD, FFD, (size_t)DD * FFD, (size_t)DD * FFD);
    tcast<<<dim3(16, 64, 2), 256, 0, stream>>>(w2, w2T, FFD, DD, (size_t)FFD * DD, (size_t)FFD * DD);
    tcast<<<dim3(500, 16, 1), 256, 0, stream>>>(w_un, wunT, DD, VV, 0, 0);

    // embed + LN1(l=0) fused
    embed_ln<<<TT, 256, 0, stream>>>(idx, tok, pos, ln1_g, ln1_b, x, h);

    for (int l = 0; l < NL; ++l) {
        mgemm<0, 64><<<dim3(48, 16), 256, 0, stream>>>(h, wqkvT + (size_t)l * 3072 * DD, nullptr, qg, TT, 3072, DD, DD);
        attn_kernel<<<512, 256, 0, stream>>>(qg, kg, vt, x);
        ln_kernel<<<TT, 256, 0, stream>>>(x, ln2_g + l * DD, ln2_b + l * DD, h);
        mgemm<1, 128><<<dim3(32, 16), 256, 0, stream>>>(h, w1T + (size_t)l * FFD * DD, b1 + (size_t)l * FFD, h1, TT, FFD, DD, DD);
        // FFN2 split-K=2: partials (z-planes) then fused reduce + next LN
        mgemm<3, 64><<<dim3(16, 16, 2), 256, 0, stream>>>(h1, w2T + (size_t)l * DD * FFD, nullptr, Pp, TT, DD, FFD / 2, FFD);
        const float* ng = (l + 1 < NL) ? (ln1_g + (l + 1) * DD) : lnf_g;
        const float* nb = (l + 1 < NL) ? (ln1_b + (l + 1) * DD) : lnf_b;
        ffn2_reduce_ln<<<TT, 256, 0, stream>>>(Pp, b2 + (size_t)l * DD, x, ng, nb, h);
    }

    // h holds LN_f(x); unembed
    mgemm256<<<dim3(1024), 512, 0, stream>>>(h, wunT, b_un, out, TT, VV, DD);
}